// Round 8
// baseline (284.871 us; speedup 1.0000x reference)
//
#include <hip/hip_runtime.h>

// ---- problem constants ----
constexpr int Bc = 4;
constexpr int Cc = 2048;
constexpr int Sc = 1024;     // H*W = 32*32
constexpr int Ntok = 4096;   // B*S
constexpr int Ec = 768;
constexpr int E3 = 2304;
constexpr int NHEAD = 12;
constexpr int GHEAD = 4;
constexpr int DGAT = 192;

typedef __attribute__((ext_vector_type(8))) short short8_t;   // bf16x8 MFMA frag
typedef __attribute__((ext_vector_type(4))) short short4_t;
typedef __attribute__((ext_vector_type(8))) unsigned short u16x8;
typedef __attribute__((ext_vector_type(4))) float f32x4;

// software RNE f32->bf16
__device__ inline unsigned short f2bf(float f) {
  unsigned int u = __builtin_bit_cast(unsigned int, f);
  u += 0x7FFFu + ((u >> 16) & 1u);
  return (unsigned short)(u >> 16);
}
__device__ inline float bf2f(unsigned short h) {
  unsigned int u = ((unsigned int)h) << 16;
  return __builtin_bit_cast(float, u);
}
// packed hw cvt: lo -> D[15:0], hi -> D[31:16] (P fragments only; verified absmax-neutral)
__device__ inline unsigned cvtpk(float lo, float hi) {
  unsigned r;
  asm("v_cvt_pk_bf16_f32 %0, %1, %2" : "=v"(r) : "v"(lo), "v"(hi));
  return r;
}

// ============ weight prep: 6 transposed + 1 identity bf16 cast ============
struct WtArgs {
  const float* src[7];
  unsigned short* dst[7];
  int K[7], N[7], mode[7];   // mode 0: dst[n][k]=src[k][n]; mode 1: dst[k][n]=src[k][n]
  int off[8];
};
__global__ __launch_bounds__(256) void k_wt(WtArgs a) {
  __shared__ float t[32][33];
  int bid = blockIdx.x;
  int w = 0;
  while (w < 6 && bid >= a.off[w + 1]) ++w;
  int local = bid - a.off[w];
  int K = a.K[w], N = a.N[w];
  int ntn = N >> 5;
  int tk = local / ntn, tn = local - tk * ntn;
  int k0 = tk * 32, n0 = tn * 32;
  int tx = threadIdx.x & 31, ty = threadIdx.x >> 5;
  const float* src = a.src[w];
  unsigned short* dst = a.dst[w];
  if (a.mode[w]) {
#pragma unroll
    for (int i = 0; i < 4; i++)
      dst[(size_t)(k0 + ty + i * 8) * N + n0 + tx] =
          f2bf(src[(size_t)(k0 + ty + i * 8) * N + n0 + tx]);
    return;
  }
#pragma unroll
  for (int i = 0; i < 4; i++)
    t[ty + i * 8][tx] = src[(size_t)(k0 + ty + i * 8) * N + n0 + tx];
  __syncthreads();
#pragma unroll
  for (int i = 0; i < 4; i++)
    dst[(size_t)(n0 + ty + i * 8) * K + k0 + tx] = f2bf(t[tx][ty + i * 8]);
}

// ============ bias2 = gp_b @ gat_w (vector-matrix), single kernel ============
__global__ __launch_bounds__(256) void k_bias2(const float* __restrict__ gat_w,
    const float* __restrict__ gp_b, float* __restrict__ bias2) {
  int m = blockIdx.x * 256 + threadIdx.x;
  float acc = 0.f;
#pragma unroll 8
  for (int j = 0; j < Ec; j++)
    acc += gp_b[j] * gat_w[(size_t)j * Ec + m];
  bias2[m] = acc;
}

// ============ LN1 pass A: partial sums over 256-c chunks ============
__global__ __launch_bounds__(256) void k_ln1_stats(const float* __restrict__ x,
    float* __restrict__ psum, float* __restrict__ pss) {
  int cc = blockIdx.x, st = blockIdx.y, b = blockIdx.z;
  int sl = threadIdx.x & 15, cl = threadIdx.x >> 4;
  int s = st * 16 + sl;
  const float* xb = x + (size_t)b * Cc * Sc + s;
  float sum = 0.f, ss = 0.f;
#pragma unroll
  for (int t = 0; t < 16; t++) {
    int c = cc * 256 + cl + t * 16;
    float v = xb[(size_t)c * Sc];
    sum += v; ss += v * v;
  }
  __shared__ float rs0[16][17], rs1[16][17];
  rs0[cl][sl] = sum; rs1[cl][sl] = ss;
  __syncthreads();
  if (cl == 0) {
    float a = 0.f, q = 0.f;
#pragma unroll
    for (int i = 0; i < 16; i++) { a += rs0[i][sl]; q += rs1[i][sl]; }
    size_t bs = (size_t)(b * Sc + st * 16 + sl);
    psum[bs * 8 + cc] = a;
    pss[bs * 8 + cc] = q;
  }
}

// ============ LN1 pass B: normalize + transpose to bf16 [M][C] ============
__global__ __launch_bounds__(256) void k_ln1_norm(const float* __restrict__ x,
    const float* __restrict__ g, const float* __restrict__ bt,
    const float* __restrict__ psum, const float* __restrict__ pss,
    unsigned short* __restrict__ out) {
  int cc = blockIdx.x, st = blockIdx.y, b = blockIdx.z;
  int sl = threadIdx.x & 15, cl = threadIdx.x >> 4;
  int s = st * 16 + sl;
  __shared__ float red[16][17];
  __shared__ float mean_s[16], rstd_s[16];
  int t8 = cl;
  size_t bsrow = (size_t)(b * Sc + st * 16 + sl);
  float v = (t8 < 8) ? psum[bsrow * 8 + t8] : pss[bsrow * 8 + (t8 - 8)];
  red[t8][sl] = v;
  __syncthreads();
  if (threadIdx.x < 16) {
    float s0 = 0.f, s1 = 0.f;
#pragma unroll
    for (int i = 0; i < 8; i++) { s0 += red[i][threadIdx.x]; s1 += red[i + 8][threadIdx.x]; }
    float mean = s0 / Cc;
    mean_s[threadIdx.x] = mean;
    rstd_s[threadIdx.x] = rsqrtf(s1 / Cc - mean * mean + 1e-5f);
  }
  __syncthreads();
  float mean = mean_s[sl], rstd = rstd_s[sl];
  const float* xb = x + (size_t)b * Cc * Sc + s;
  __shared__ unsigned short Tc[16][136];
  int cb = cc * 128;
#pragma unroll
  for (int t = 0; t < 8; t++) {
    int c = cb + cl + t * 16;
    float xv = xb[(size_t)c * Sc];
    Tc[sl][cl + t * 16] = f2bf((xv - mean) * rstd * g[c] + bt[c]);
  }
  __syncthreads();
  int rl = threadIdx.x >> 4, el = threadIdx.x & 15;
  unsigned short* ob = out + ((size_t)(b * Sc) + st * 16 + rl) * Cc + cb;
  *(u16x8*)&ob[el * 8] = *(const u16x8*)&Tc[rl][el * 8];
}

// ============ bf16 MFMA GEMM, 512 thr = 8 waves (2Mx4N), reg-staged double-buffer ============
template<int EPI, int OUTM>
__global__ __launch_bounds__(512) void gemm_bf16(
    const unsigned short* __restrict__ A, const unsigned short* __restrict__ Bt,
    const float* __restrict__ bias, const float* __restrict__ res,
    float* __restrict__ Cf, unsigned short* __restrict__ Cb,
    int M, int N, int K) {
  __shared__ unsigned short As[128][72];
  __shared__ unsigned short Bs[128][72];
  int tid = threadIdx.x;
  int w = tid >> 6, lane = tid & 63, g = lane >> 4, l16 = lane & 15;
  int wm = w >> 2, wn = w & 3;
  int m0 = blockIdx.y * 128, n0 = blockIdx.x * 128;
  int r0 = tid >> 3, ch0 = (tid & 7) * 8;
  int r1 = r0 + 64;
  const unsigned short* Arow0 = A + (size_t)(m0 + r0) * K + ch0;
  const unsigned short* Arow1 = A + (size_t)(m0 + r1) * K + ch0;
  const unsigned short* Brow0 = Bt + (size_t)(n0 + r0) * K + ch0;
  const unsigned short* Brow1 = Bt + (size_t)(n0 + r1) * K + ch0;
  u16x8 ra0 = *(const u16x8*)Arow0;
  u16x8 ra1 = *(const u16x8*)Arow1;
  u16x8 rb0 = *(const u16x8*)Brow0;
  u16x8 rb1 = *(const u16x8*)Brow1;
  f32x4 acc[4][2] = {};
  for (int k0 = 0; k0 < K; k0 += 64) {
    __syncthreads();
    *(u16x8*)&As[r0][ch0] = ra0;
    *(u16x8*)&As[r1][ch0] = ra1;
    *(u16x8*)&Bs[r0][ch0] = rb0;
    *(u16x8*)&Bs[r1][ch0] = rb1;
    __syncthreads();
    if (k0 + 64 < K) {
      ra0 = *(const u16x8*)(Arow0 + k0 + 64);
      ra1 = *(const u16x8*)(Arow1 + k0 + 64);
      rb0 = *(const u16x8*)(Brow0 + k0 + 64);
      rb1 = *(const u16x8*)(Brow1 + k0 + 64);
    }
#pragma unroll
    for (int ks = 0; ks < 2; ks++) {
      short8_t af[4], bf[2];
#pragma unroll
      for (int i = 0; i < 4; i++)
        af[i] = *(const short8_t*)&As[wm * 64 + i * 16 + l16][ks * 32 + g * 8];
#pragma unroll
      for (int j = 0; j < 2; j++)
        bf[j] = *(const short8_t*)&Bs[wn * 32 + j * 16 + l16][ks * 32 + g * 8];
#pragma unroll
      for (int mi = 0; mi < 4; mi++)
#pragma unroll
        for (int ni = 0; ni < 2; ni++)
          acc[mi][ni] = __builtin_amdgcn_mfma_f32_16x16x32_bf16(af[mi], bf[ni], acc[mi][ni], 0, 0, 0);
    }
  }
#pragma unroll
  for (int mi = 0; mi < 4; mi++) {
#pragma unroll
    for (int ni = 0; ni < 2; ni++) {
      int n = n0 + wn * 32 + ni * 16 + l16;
      float bv = 0.f;
      if (EPI != 0) bv = bias[n];
#pragma unroll
      for (int r = 0; r < 4; r++) {
        int m = m0 + wm * 64 + mi * 16 + g * 4 + r;
        float c = acc[mi][ni][r] + bv;
        if (EPI == 2) c += res[(size_t)m * N + n];
        if (EPI == 3) c = 0.5f * c * (1.f + erff(c * 0.70710678118f));
        if (OUTM & 1) Cf[(size_t)m * N + n] = c;
        if (OUTM & 2) Cb[(size_t)m * N + n] = f2bf(c);
      }
    }
  }
}

// ============ MHSA: swapped-QK MFMA flash, XCD-grouped grid, defer-max, cvt_pk P ============
__global__ __launch_bounds__(256) void k_attn_mfma(const unsigned short* __restrict__ qkv,
    unsigned short* __restrict__ o) {
  __shared__ unsigned short Ks[64][72];     // [key][dh]
  __shared__ unsigned short Vs[4608];       // subtiled, dd-stride 72, kk-stride 288
  __shared__ unsigned short Plb[4][16][72]; // per-wave P rows [q][k]
  // XCD-grouped mapping: all 16 qt-blocks of one (h,b) land on one XCD (round-robin id%8)
  int fid = blockIdx.x;
  int xcd = fid & 7, t = fid >> 3;
  int qt = t & 15;
  int hb = (t >> 4) * 8 + xcd;     // 0..47
  int h = hb % NHEAD, b = hb / NHEAD;
  int tid = threadIdx.x;
  int w = tid >> 6, lane = tid & 63;
  int g = lane >> 4, l16 = lane & 15;
  const unsigned short* base  = qkv + (size_t)b * Sc * E3;
  const unsigned short* kbase = base + Ec + h * 64;
  const unsigned short* vbase = base + 2 * Ec + h * 64;
  int q0 = qt * 64 + w * 16;

  // Q frags (B-operand), pre-scaled by pow2 1/8
  short8_t qf[2];
#pragma unroll
  for (int ks = 0; ks < 2; ks++) {
    short8_t f = *(const short8_t*)&base[(size_t)(q0 + l16) * E3 + h * 64 + ks * 32 + g * 8];
#pragma unroll
    for (int e = 0; e < 8; e++)
      f[e] = (short)f2bf(bf2f((unsigned short)f[e]) * 0.125f);
    qf[ks] = f;
  }

  // staging geometry
  int r0s = tid >> 3, ch0s = (tid & 7) * 8;
  int r1s = r0s + 32;
  int voff0 = (r0s >> 2) * 288 + (ch0s >> 4) * 72 + (r0s & 3) * 16 + ((ch0s >> 3) & 1) * 8;
  int voff1 = (r1s >> 2) * 288 + (ch0s >> 4) * 72 + (r1s & 3) * 16 + ((ch0s >> 3) & 1) * 8;
  const unsigned short* krow0 = kbase + (size_t)r0s * E3 + ch0s;
  const unsigned short* krow1 = kbase + (size_t)r1s * E3 + ch0s;
  const unsigned short* vrow0 = vbase + (size_t)r0s * E3 + ch0s;
  const unsigned short* vrow1 = vbase + (size_t)r1s * E3 + ch0s;
  constexpr size_t KTS = (size_t)64 * E3;

  u16x8 rk0 = *(const u16x8*)krow0;
  u16x8 rk1 = *(const u16x8*)krow1;
  u16x8 rv0 = *(const u16x8*)vrow0;
  u16x8 rv1 = *(const u16x8*)vrow1;

  f32x4 o_acc[4] = {};
  float m_r = -1e30f, l_r = 0.f;    // per-lane state for q-row = l16

  for (int kt = 0; kt < 16; kt++) {
    __syncthreads();
    *(u16x8*)&Ks[r0s][ch0s] = rk0;
    *(u16x8*)&Ks[r1s][ch0s] = rk1;
    *(u16x8*)&Vs[voff0] = rv0;
    *(u16x8*)&Vs[voff1] = rv1;
    __syncthreads();
    if (kt < 15) {
      size_t off = (size_t)(kt + 1) * KTS;
      rk0 = *(const u16x8*)(krow0 + off);
      rk1 = *(const u16x8*)(krow1 + off);
      rv0 = *(const u16x8*)(vrow0 + off);
      rv1 = *(const u16x8*)(vrow1 + off);
    }

    // S^T = K @ Q^T : row = k_local, col = q = l16
    f32x4 s_acc[4] = {};
#pragma unroll
    for (int nt = 0; nt < 4; nt++) {
#pragma unroll
      for (int ks = 0; ks < 2; ks++) {
        short8_t kf = *(const short8_t*)&Ks[nt * 16 + l16][ks * 32 + g * 8];
        s_acc[nt] = __builtin_amdgcn_mfma_f32_16x16x32_bf16(kf, qf[ks], s_acc[nt], 0, 0, 0);
      }
    }

    // tile max for q-row l16: 15 in-lane + 2 shfl
    float mx = s_acc[0][0];
#pragma unroll
    for (int nt = 0; nt < 4; nt++)
#pragma unroll
      for (int r = 0; r < 4; r++) mx = fmaxf(mx, s_acc[nt][r]);
    mx = fmaxf(mx, __shfl_xor(mx, 16));
    mx = fmaxf(mx, __shfl_xor(mx, 32));

    // defer-max (T13): only rescale when some row grew by > 8
    if (!__all(mx - m_r <= 8.f)) {
      float mn = fmaxf(m_r, mx);
      float sc = __expf(m_r - mn);
      m_r = mn;
      l_r *= sc;
      float osc[4];
#pragma unroll
      for (int r = 0; r < 4; r++) osc[r] = __shfl(sc, g * 4 + r);
#pragma unroll
      for (int dt = 0; dt < 4; dt++)
#pragma unroll
        for (int r = 0; r < 4; r++) o_acc[dt][r] *= osc[r];
    }

    float ts = 0.f;
#pragma unroll
    for (int nt = 0; nt < 4; nt++)
#pragma unroll
      for (int r = 0; r < 4; r++) {
        float pv = __expf(s_acc[nt][r] - m_r);
        s_acc[nt][r] = pv;
        ts += pv;
      }
    ts += __shfl_xor(ts, 16);
    ts += __shfl_xor(ts, 32);
    l_r += ts;

    // P^T -> Plb[q][k], single-instruction packed cvt per pair
#pragma unroll
    for (int nt = 0; nt < 4; nt++) {
      *(unsigned*)&Plb[w][l16][nt * 16 + g * 4] = cvtpk(s_acc[nt][0], s_acc[nt][1]);
      *(unsigned*)&Plb[w][l16][nt * 16 + g * 4 + 2] = cvtpk(s_acc[nt][2], s_acc[nt][3]);
    }

    // O += P @ V ; A-frag rows = q = l16, contiguous reads
#pragma unroll
    for (int ks = 0; ks < 2; ks++) {
      short8_t pf = *(const short8_t*)&Plb[w][l16][ks * 32 + g * 8];
      short4_t lo0, lo1, lo2, lo3, hi0, hi1, hi2, hi3;
      unsigned a0 = (unsigned)(uintptr_t)&Vs[(ks * 8 + g * 2) * 288 + 0 * 72 + l16] * 1u;
      unsigned a1 = a0 + 144, a2 = a0 + 288, a3 = a0 + 432;
      asm volatile("ds_read_b64_tr_b16 %0, %1" : "=v"(lo0) : "v"(a0));
      asm volatile("ds_read_b64_tr_b16 %0, %1 offset:576" : "=v"(hi0) : "v"(a0));
      asm volatile("ds_read_b64_tr_b16 %0, %1" : "=v"(lo1) : "v"(a1));
      asm volatile("ds_read_b64_tr_b16 %0, %1 offset:576" : "=v"(hi1) : "v"(a1));
      asm volatile("ds_read_b64_tr_b16 %0, %1" : "=v"(lo2) : "v"(a2));
      asm volatile("ds_read_b64_tr_b16 %0, %1 offset:576" : "=v"(hi2) : "v"(a2));
      asm volatile("ds_read_b64_tr_b16 %0, %1" : "=v"(lo3) : "v"(a3));
      asm volatile("ds_read_b64_tr_b16 %0, %1 offset:576" : "=v"(hi3) : "v"(a3));
      asm volatile("s_waitcnt lgkmcnt(0)");
      __builtin_amdgcn_sched_barrier(0);
      short4_t lo[4] = {lo0, lo1, lo2, lo3};
      short4_t hi[4] = {hi0, hi1, hi2, hi3};
#pragma unroll
      for (int dt = 0; dt < 4; dt++) {
        short8_t vf;
#pragma unroll
        for (int e = 0; e < 4; e++) { vf[e] = lo[dt][e]; vf[4 + e] = hi[dt][e]; }
        o_acc[dt] = __builtin_amdgcn_mfma_f32_16x16x32_bf16(pf, vf, o_acc[dt], 0, 0, 0);
      }
    }
  }

  // normalize: row q'=g*4+r uses l from lane q'
  float linv = 1.f / l_r;
  float inv4[4];
#pragma unroll
  for (int r = 0; r < 4; r++) inv4[r] = __shfl(linv, g * 4 + r);
  unsigned short* obase = o + (size_t)(b * Sc + q0) * Ec + h * 64;
#pragma unroll
  for (int r = 0; r < 4; r++) {
    int qrow = g * 4 + r;
#pragma unroll
    for (int dt = 0; dt < 4; dt++)
      obase[(size_t)qrow * Ec + dt * 16 + l16] = f2bf(o_acc[dt][r] * inv4[r]);
  }
}

// ============ LN over rows of E=768 (row-major outs) ============
template<int MODE>
__global__ __launch_bounds__(256) void k_lnrow(const float* __restrict__ in,
    const float* __restrict__ g, const float* __restrict__ bt,
    float* __restrict__ outf, unsigned short* __restrict__ outb) {
  int row = blockIdx.x;
  int tid = threadIdx.x;
  __shared__ float buf[Ec];
  __shared__ float rsum[4], rss[4];
  float sum = 0.f, ss = 0.f;
  for (int i = tid; i < Ec; i += 256) {
    float v = in[(size_t)row * Ec + i];
    buf[i] = v; sum += v; ss += v * v;
  }
#pragma unroll
  for (int off = 32; off > 0; off >>= 1) {
    sum += __shfl_xor(sum, off); ss += __shfl_xor(ss, off);
  }
  if ((tid & 63) == 0) { rsum[tid >> 6] = sum; rss[tid >> 6] = ss; }
  __syncthreads();
  sum = rsum[0] + rsum[1] + rsum[2] + rsum[3];
  ss = rss[0] + rss[1] + rss[2] + rss[3];
  float mean = sum / Ec;
  float rstd = rsqrtf(ss / Ec - mean * mean + 1e-5f);
  for (int i = tid; i < Ec; i += 256) {
    float v = (buf[i] - mean) * rstd * g[i] + bt[i];
    if (MODE == 2) outf[(size_t)row * Ec + i] = v;
    outb[(size_t)row * Ec + i] = f2bf(v);
  }
}

// ============ final LN: out = LN(n3+mlp) transposed to [B,E,H,W] ============
__global__ __launch_bounds__(256) void k_lnout(const float* __restrict__ in,
    const float* __restrict__ res, const float* __restrict__ g,
    const float* __restrict__ bt, float* __restrict__ out) {
  int r0 = blockIdx.x * 16;
  int b = r0 >> 10, s0 = r0 & 1023;
  __shared__ float Tr[16][772];
  __shared__ float mean_s[16], rstd_s[16];
  int rl = threadIdx.x >> 4, el = threadIdx.x & 15;
  const float* ip = in + (size_t)(r0 + rl) * Ec;
  const float* rp = res + (size_t)(r0 + rl) * Ec;
  float sum = 0.f, ss = 0.f;
  for (int i = el; i < Ec; i += 16) {
    float v = ip[i] + rp[i];
    Tr[rl][i] = v; sum += v; ss += v * v;
  }
#pragma unroll
  for (int off = 8; off; off >>= 1) {
    sum += __shfl_xor(sum, off); ss += __shfl_xor(ss, off);
  }
  if (el == 0) {
    float mean = sum / Ec;
    mean_s[rl] = mean;
    rstd_s[rl] = rsqrtf(ss / Ec - mean * mean + 1e-5f);
  }
  __syncthreads();
  int sl = threadIdx.x & 15, il = threadIdx.x >> 4;
  float mean = mean_s[sl], rstd = rstd_s[sl];
  for (int i = il; i < Ec; i += 16)
    out[((size_t)b * Ec + i) * Sc + s0 + sl] = (Tr[sl][i] - mean) * rstd * g[i] + bt[i];
}

// ============ per-node attention coefficients a_s, a_d (bf16 hN) ============
__global__ __launch_bounds__(256) void k_asd(const unsigned short* __restrict__ hNb,
    const float* __restrict__ att_src, const float* __restrict__ att_dst,
    float* __restrict__ a_s, float* __restrict__ a_d) {
  int n = blockIdx.x * 4 + (threadIdx.x >> 6);
  int lane = threadIdx.x & 63;
  const unsigned short* hrow = hNb + (size_t)n * Ec;
#pragma unroll
  for (int h = 0; h < GHEAD; h++) {
    float ps = 0.f, pd = 0.f;
    for (int d = lane; d < DGAT; d += 64) {
      float v = bf2f(hrow[h * DGAT + d]);
      ps += v * att_src[h * DGAT + d];
      pd += v * att_dst[h * DGAT + d];
    }
#pragma unroll
    for (int off = 32; off > 0; off >>= 1) {
      ps += __shfl_xor(ps, off); pd += __shfl_xor(pd, off);
    }
    if (lane == 0) { a_s[n * GHEAD + h] = ps; a_d[n * GHEAD + h] = pd; }
  }
}

// ============ GAT stencil (bf16 hN) ============
__global__ __launch_bounds__(256) void k_gat(const unsigned short* __restrict__ hNb,
    const float* __restrict__ a_s, const float* __restrict__ a_d,
    const float* __restrict__ x_attn, const float* __restrict__ gat_b,
    float* __restrict__ x_after) {
  int n = blockIdx.x;
  int b = n >> 10, s = n & 1023, r = s >> 5, c = s & 31;
  __shared__ int nbr[9];
  __shared__ float alpha[GHEAD][9];
  int tid = threadIdx.x;
  if (tid < 9) {
    int dr = tid / 3 - 1, dc = tid % 3 - 1;
    int rr = r + dr, cc = c + dc;
    int ok = (rr >= 0 && rr < 32 && cc >= 0 && cc < 32);
    if (dr == -1 && dc == 1 && cc == 31) ok = 0;
    if (dr == 1 && dc == -1 && c == 31) ok = 0;
    nbr[tid] = ok ? ((b << 10) + (rr << 5) + cc) : -1;
  }
  __syncthreads();
  if (tid < GHEAD) {
    int h = tid;
    float ad = a_d[n * GHEAD + h];
    float ev[9]; float m = -1e30f;
#pragma unroll
    for (int j = 0; j < 9; j++) {
      if (nbr[j] >= 0) {
        float e = a_s[nbr[j] * GHEAD + h] + ad;
        e = e > 0.f ? e : 0.2f * e;
        ev[j] = e; m = fmaxf(m, e);
      } else ev[j] = -1e30f;
    }
    float den = 0.f;
#pragma unroll
    for (int j = 0; j < 9; j++) {
      float x = (nbr[j] >= 0) ? expf(ev[j] - m) : 0.f;
      ev[j] = x; den += x;
    }
    float inv = 1.f / den;
#pragma unroll
    for (int j = 0; j < 9; j++) alpha[h][j] = ev[j] * inv;
  }
  __syncthreads();
  for (int e = tid; e < Ec; e += 256) {
    int h = e / DGAT;
    float acc = 0.f;
#pragma unroll
    for (int j = 0; j < 9; j++) {
      int nj = nbr[j];
      if (nj >= 0) acc += alpha[h][j] * bf2f(hNb[(size_t)nj * Ec + e]);
    }
    float v = acc + gat_b[e];
    v = v > 0.f ? v : expf(v) - 1.f;
    x_after[(size_t)n * Ec + e] = x_attn[(size_t)n * Ec + e] + v;
  }
}

extern "C" void kernel_launch(void* const* d_in, const int* in_sizes, int n_in,
                              void* d_out, int out_size, void* d_ws, size_t ws_size,
                              hipStream_t stream) {
  (void)in_sizes; (void)n_in; (void)out_size; (void)ws_size;
  const float* x      = (const float*)d_in[0];
  const float* ln1_g  = (const float*)d_in[1];
  const float* ln1_b  = (const float*)d_in[2];
  const float* proj_w = (const float*)d_in[3];
  const float* proj_b = (const float*)d_in[4];
  const float* wqkv   = (const float*)d_in[5];
  const float* bqkv   = (const float*)d_in[6];
  const float* wo     = (const float*)d_in[7];
  const float* bo     = (const float*)d_in[8];
  const float* ln2_g  = (const float*)d_in[9];
  const float* ln2_b  = (const float*)d_in[10];
  const float* gp_w   = (const float*)d_in[11];
  const float* gp_b   = (const float*)d_in[12];
  const float* gat_w  = (const float*)d_in[13];
  const float* att_src= (const float*)d_in[14];
  const float* att_dst= (const float*)d_in[15];
  const float* gat_b  = (const float*)d_in[16];
  const float* ln3_g  = (const float*)d_in[17];
  const float* ln3_b  = (const float*)d_in[18];
  const float* mlp_w1 = (const float*)d_in[19];
  const float* mlp_b1 = (const float*)d_in[20];
  const float* mlp_w2 = (const float*)d_in[21];
  const float* mlp_b2 = (const float*)d_in[22];
  const float* fn_g   = (const float*)d_in[23];
  const float* fn_b   = (const float*)d_in[24];
  float* out = (float*)d_out;

  // ---- workspace layout ----
  char* p = (char*)d_ws;
  auto alloc = [&](size_t bytes) { char* q = p; p += (bytes + 255) & ~(size_t)255; return q; };
  char* regA      = alloc((size_t)Ntok * E3 * 2);            // n1_bf -> qkv_bf
  unsigned short* n1_bf  = (unsigned short*)regA;
  unsigned short* qkv_bf = (unsigned short*)regA;
  unsigned short* proj_wt = (unsigned short*)alloc((size_t)Ec * Cc * 2);
  unsigned short* wqkv_t  = (unsigned short*)alloc((size_t)E3 * Ec * 2);
  unsigned short* wo_t    = (unsigned short*)alloc((size_t)Ec * Ec * 2);
  unsigned short* gp_bf   = (unsigned short*)alloc((size_t)Ec * Ec * 2);  // identity cast
  unsigned short* gat_t   = (unsigned short*)alloc((size_t)Ec * Ec * 2);
  unsigned short* m1_t    = (unsigned short*)alloc((size_t)Ec * Ec * 2);
  unsigned short* m2_t    = (unsigned short*)alloc((size_t)Ec * Ec * 2);
  unsigned short* gpgat_t = (unsigned short*)alloc((size_t)Ec * Ec * 2);  // (gp_w@gat_w)^T bf16
  float* bias2  = (float*)alloc((size_t)Ec * 4);
  float* v_in   = (float*)alloc((size_t)Ntok * Ec * 4);
  unsigned short* v_in_bf = (unsigned short*)alloc((size_t)Ntok * Ec * 2);
  unsigned short* regE    = (unsigned short*)alloc((size_t)Ntok * Ec * 2); // o_bf -> h1_bf
  float* regF   = (float*)alloc((size_t)Ntok * Ec * 4);      // x_attn -> n3 f32
  unsigned short* regG    = (unsigned short*)alloc((size_t)Ntok * Ec * 2); // n2_bf -> n3_bf
  unsigned short* hN_bf   = (unsigned short*)alloc((size_t)Ntok * Ec * 2);
  float* regJ   = (float*)alloc((size_t)Ntok * Ec * 4);      // x_after -> mlp_out
  float* a_s    = (float*)alloc((size_t)Ntok * GHEAD * 4);
  float* a_d    = (float*)alloc((size_t)Ntok * GHEAD * 4);
  float* psum   = (float*)alloc((size_t)Ntok * 8 * 4);
  float* pss    = (float*)alloc((size_t)Ntok * 8 * 4);

  unsigned short* o_bf   = regE;
  unsigned short* h1_bf  = regE;
  float* x_attn = regF;
  float* n3_f   = regF;
  unsigned short* n2_bf  = regG;
  unsigned short* n3_bf  = regG;
  float* x_after = regJ;
  float* mlp_out = regJ;

  // 0) weights -> bf16 (6 transposed + gp identity)
  WtArgs wa;
  wa.src[0] = proj_w; wa.dst[0] = proj_wt; wa.K[0] = Cc; wa.N[0] = Ec;  wa.mode[0] = 0;
  wa.src[1] = wqkv;   wa.dst[1] = wqkv_t;  wa.K[1] = Ec; wa.N[1] = E3;  wa.mode[1] = 0;
  wa.src[2] = wo;     wa.dst[2] = wo_t;    wa.K[2] = Ec; wa.N[2] = Ec;  wa.mode[2] = 0;
  wa.src[3] = gat_w;  wa.dst[3] = gat_t;   wa.K[3] = Ec; wa.N[3] = Ec;  wa.mode[3] = 0;
  wa.src[4] = mlp_w1; wa.dst[4] = m1_t;    wa.K[4] = Ec; wa.N[4] = Ec;  wa.mode[4] = 0;
  wa.src[5] = mlp_w2; wa.dst[5] = m2_t;    wa.K[5] = Ec; wa.N[5] = Ec;  wa.mode[5] = 0;
  wa.src[6] = gp_w;   wa.dst[6] = gp_bf;   wa.K[6] = Ec; wa.N[6] = Ec;  wa.mode[6] = 1;
  int cum = 0;
  for (int i = 0; i < 7; i++) { wa.off[i] = cum; cum += (wa.K[i] >> 5) * (wa.N[i] >> 5); }
  wa.off[7] = cum;
  k_wt<<<cum, 256, 0, stream>>>(wa);

  // 0b) fused gp@gat weight + bias2
  k_bias2<<<3, 256, 0, stream>>>(gat_w, gp_b, bias2);
  gemm_bf16<0, 2><<<dim3(Ec / 128, Ec / 128), 512, 0, stream>>>(
      gat_t, gp_bf, nullptr, nullptr, nullptr, gpgat_t, Ec, Ec, Ec);

  // 1) LN1 two-pass -> bf16 [M][C]
  k_ln1_stats<<<dim3(8, 64, 4), 256, 0, stream>>>(x, psum, pss);
  k_ln1_norm<<<dim3(16, 64, 4), 256, 0, stream>>>(x, ln1_g, ln1_b, psum, pss, n1_bf);
  // 2) v_in = n1 @ proj_w + proj_b  (f32 + bf16 out)
  gemm_bf16<1, 3><<<dim3(Ec / 128, Ntok / 128), 512, 0, stream>>>(
      n1_bf, proj_wt, proj_b, nullptr, v_in, v_in_bf, Ntok, Ec, Cc);
  // 3) qkv = v_in @ wqkv + bqkv  (bf16 out)
  gemm_bf16<1, 2><<<dim3(E3 / 128, Ntok / 128), 512, 0, stream>>>(
      v_in_bf, wqkv_t, bqkv, nullptr, nullptr, qkv_bf, Ntok, E3, Ec);
  // 4) attention (XCD-grouped 1D grid)
  k_attn_mfma<<<16 * NHEAD * Bc, 256, 0, stream>>>(qkv_bf, o_bf);
  // 5) x_attn = v_in + o @ wo + bo  (f32)
  gemm_bf16<2, 1><<<dim3(Ec / 128, Ntok / 128), 512, 0, stream>>>(
      o_bf, wo_t, bo, v_in, x_attn, nullptr, Ntok, Ec, Ec);
  // 6) n2 = LN(x_attn) -> bf16
  k_lnrow<0><<<Ntok, 256, 0, stream>>>(x_attn, ln2_g, ln2_b, nullptr, n2_bf);
  // 7+8 fused) hN = n2 @ (gp_w@gat_w) + gp_b@gat_w -> bf16
  gemm_bf16<1, 2><<<dim3(Ec / 128, Ntok / 128), 512, 0, stream>>>(
      n2_bf, gpgat_t, bias2, nullptr, nullptr, hN_bf, Ntok, Ec, Ec);
  // 9) a_s, a_d
  k_asd<<<Ntok / 4, 256, 0, stream>>>(hN_bf, att_src, att_dst, a_s, a_d);
  // 10) GAT aggregate + elu + residual -> x_after
  k_gat<<<Ntok, 256, 0, stream>>>(hN_bf, a_s, a_d, x_attn, gat_b, x_after);
  // 11) n3 = LN(x_after) -> f32 + bf16
  k_lnrow<2><<<Ntok, 256, 0, stream>>>(x_after, ln3_g, ln3_b, n3_f, n3_bf);
  // 12) h1 = gelu(n3 @ mlp_w1 + mlp_b1) -> bf16
  gemm_bf16<3, 2><<<dim3(Ec / 128, Ntok / 128), 512, 0, stream>>>(
      n3_bf, m1_t, mlp_b1, nullptr, nullptr, h1_bf, Ntok, Ec, Ec);
  // 13) mlp = h1 @ mlp_w2 + mlp_b2 -> f32
  gemm_bf16<1, 1><<<dim3(Ec / 128, Ntok / 128), 512, 0, stream>>>(
      h1_bf, m2_t, mlp_b2, nullptr, mlp_out, nullptr, Ntok, Ec, Ec);
  // 14) out = LN(n3 + mlp), transposed to [B,E,H,W]
  k_lnout<<<256, 256, 0, stream>>>(n3_f, mlp_out, fn_g, fn_b, out);
}

// Round 9
// 256.215 us; speedup vs baseline: 1.1118x; 1.1118x over previous
//
#include <hip/hip_runtime.h>

// ---- problem constants ----
constexpr int Bc = 4;
constexpr int Cc = 2048;
constexpr int Sc = 1024;     // H*W = 32*32
constexpr int Ntok = 4096;   // B*S
constexpr int Ec = 768;
constexpr int E3 = 2304;
constexpr int NHEAD = 12;
constexpr int GHEAD = 4;
constexpr int DGAT = 192;

typedef __attribute__((ext_vector_type(8))) short short8_t;   // bf16x8 MFMA frag
typedef __attribute__((ext_vector_type(4))) short short4_t;
typedef __attribute__((ext_vector_type(8))) unsigned short u16x8;
typedef __attribute__((ext_vector_type(4))) float f32x4;

// software RNE f32->bf16
__device__ inline unsigned short f2bf(float f) {
  unsigned int u = __builtin_bit_cast(unsigned int, f);
  u += 0x7FFFu + ((u >> 16) & 1u);
  return (unsigned short)(u >> 16);
}
__device__ inline float bf2f(unsigned short h) {
  unsigned int u = ((unsigned int)h) << 16;
  return __builtin_bit_cast(float, u);
}
// packed hw cvt: lo -> D[15:0], hi -> D[31:16] (P fragments only; verified absmax-neutral)
__device__ inline unsigned cvtpk(float lo, float hi) {
  unsigned r;
  asm("v_cvt_pk_bf16_f32 %0, %1, %2" : "=v"(r) : "v"(lo), "v"(hi));
  return r;
}

// ============ weight prep: 6 transposed + 1 identity bf16 cast ============
struct WtArgs {
  const float* src[7];
  unsigned short* dst[7];
  int K[7], N[7], mode[7];   // mode 0: dst[n][k]=src[k][n]; mode 1: dst[k][n]=src[k][n]
  int off[8];
};
__global__ __launch_bounds__(256) void k_wt(WtArgs a) {
  __shared__ float t[32][33];
  int bid = blockIdx.x;
  int w = 0;
  while (w < 6 && bid >= a.off[w + 1]) ++w;
  int local = bid - a.off[w];
  int K = a.K[w], N = a.N[w];
  int ntn = N >> 5;
  int tk = local / ntn, tn = local - tk * ntn;
  int k0 = tk * 32, n0 = tn * 32;
  int tx = threadIdx.x & 31, ty = threadIdx.x >> 5;
  const float* src = a.src[w];
  unsigned short* dst = a.dst[w];
  if (a.mode[w]) {
#pragma unroll
    for (int i = 0; i < 4; i++)
      dst[(size_t)(k0 + ty + i * 8) * N + n0 + tx] =
          f2bf(src[(size_t)(k0 + ty + i * 8) * N + n0 + tx]);
    return;
  }
#pragma unroll
  for (int i = 0; i < 4; i++)
    t[ty + i * 8][tx] = src[(size_t)(k0 + ty + i * 8) * N + n0 + tx];
  __syncthreads();
#pragma unroll
  for (int i = 0; i < 4; i++)
    dst[(size_t)(n0 + ty + i * 8) * K + k0 + tx] = f2bf(t[tx][ty + i * 8]);
}

// ============ bias2 = gp_b @ gat_w: parallel partials (3x8 grid) + reduce ============
__global__ __launch_bounds__(256) void k_bias2p(const float* __restrict__ gat_w,
    const float* __restrict__ gp_b, float* __restrict__ part) {
  int m = blockIdx.x * 256 + threadIdx.x;
  int jc = blockIdx.y;
  float acc = 0.f;
#pragma unroll 8
  for (int j = jc * 96; j < jc * 96 + 96; j++)
    acc += gp_b[j] * gat_w[(size_t)j * Ec + m];
  part[jc * Ec + m] = acc;
}
__global__ __launch_bounds__(256) void k_bias2r(const float* __restrict__ part,
    float* __restrict__ bias2) {
  int m = blockIdx.x * 256 + threadIdx.x;
  float acc = 0.f;
#pragma unroll
  for (int j = 0; j < 8; j++) acc += part[j * Ec + m];
  bias2[m] = acc;
}

// ============ LN1 pass A: partial sums over 256-c chunks ============
__global__ __launch_bounds__(256) void k_ln1_stats(const float* __restrict__ x,
    float* __restrict__ psum, float* __restrict__ pss) {
  int cc = blockIdx.x, st = blockIdx.y, b = blockIdx.z;
  int sl = threadIdx.x & 15, cl = threadIdx.x >> 4;
  int s = st * 16 + sl;
  const float* xb = x + (size_t)b * Cc * Sc + s;
  float sum = 0.f, ss = 0.f;
#pragma unroll
  for (int t = 0; t < 16; t++) {
    int c = cc * 256 + cl + t * 16;
    float v = xb[(size_t)c * Sc];
    sum += v; ss += v * v;
  }
  __shared__ float rs0[16][17], rs1[16][17];
  rs0[cl][sl] = sum; rs1[cl][sl] = ss;
  __syncthreads();
  if (cl == 0) {
    float a = 0.f, q = 0.f;
#pragma unroll
    for (int i = 0; i < 16; i++) { a += rs0[i][sl]; q += rs1[i][sl]; }
    size_t bs = (size_t)(b * Sc + st * 16 + sl);
    psum[bs * 8 + cc] = a;
    pss[bs * 8 + cc] = q;
  }
}

// ============ LN1 pass B: normalize + transpose to bf16 [M][C] ============
__global__ __launch_bounds__(256) void k_ln1_norm(const float* __restrict__ x,
    const float* __restrict__ g, const float* __restrict__ bt,
    const float* __restrict__ psum, const float* __restrict__ pss,
    unsigned short* __restrict__ out) {
  int cc = blockIdx.x, st = blockIdx.y, b = blockIdx.z;
  int sl = threadIdx.x & 15, cl = threadIdx.x >> 4;
  int s = st * 16 + sl;
  __shared__ float red[16][17];
  __shared__ float mean_s[16], rstd_s[16];
  int t8 = cl;
  size_t bsrow = (size_t)(b * Sc + st * 16 + sl);
  float v = (t8 < 8) ? psum[bsrow * 8 + t8] : pss[bsrow * 8 + (t8 - 8)];
  red[t8][sl] = v;
  __syncthreads();
  if (threadIdx.x < 16) {
    float s0 = 0.f, s1 = 0.f;
#pragma unroll
    for (int i = 0; i < 8; i++) { s0 += red[i][threadIdx.x]; s1 += red[i + 8][threadIdx.x]; }
    float mean = s0 / Cc;
    mean_s[threadIdx.x] = mean;
    rstd_s[threadIdx.x] = rsqrtf(s1 / Cc - mean * mean + 1e-5f);
  }
  __syncthreads();
  float mean = mean_s[sl], rstd = rstd_s[sl];
  const float* xb = x + (size_t)b * Cc * Sc + s;
  __shared__ unsigned short Tc[16][136];
  int cb = cc * 128;
#pragma unroll
  for (int t = 0; t < 8; t++) {
    int c = cb + cl + t * 16;
    float xv = xb[(size_t)c * Sc];
    Tc[sl][cl + t * 16] = f2bf((xv - mean) * rstd * g[c] + bt[c]);
  }
  __syncthreads();
  int rl = threadIdx.x >> 4, el = threadIdx.x & 15;
  unsigned short* ob = out + ((size_t)(b * Sc) + st * 16 + rl) * Cc + cb;
  *(u16x8*)&ob[el * 8] = *(const u16x8*)&Tc[rl][el * 8];
}

// ============ bf16 MFMA GEMM, 512 thr = 8 waves (2Mx4N), reg-staged double-buffer ============
template<int EPI, int OUTM>
__global__ __launch_bounds__(512) void gemm_bf16(
    const unsigned short* __restrict__ A, const unsigned short* __restrict__ Bt,
    const float* __restrict__ bias, const float* __restrict__ res,
    float* __restrict__ Cf, unsigned short* __restrict__ Cb,
    int M, int N, int K) {
  __shared__ unsigned short As[128][72];
  __shared__ unsigned short Bs[128][72];
  int tid = threadIdx.x;
  int w = tid >> 6, lane = tid & 63, g = lane >> 4, l16 = lane & 15;
  int wm = w >> 2, wn = w & 3;
  int m0 = blockIdx.y * 128, n0 = blockIdx.x * 128;
  int r0 = tid >> 3, ch0 = (tid & 7) * 8;
  int r1 = r0 + 64;
  const unsigned short* Arow0 = A + (size_t)(m0 + r0) * K + ch0;
  const unsigned short* Arow1 = A + (size_t)(m0 + r1) * K + ch0;
  const unsigned short* Brow0 = Bt + (size_t)(n0 + r0) * K + ch0;
  const unsigned short* Brow1 = Bt + (size_t)(n0 + r1) * K + ch0;
  u16x8 ra0 = *(const u16x8*)Arow0;
  u16x8 ra1 = *(const u16x8*)Arow1;
  u16x8 rb0 = *(const u16x8*)Brow0;
  u16x8 rb1 = *(const u16x8*)Brow1;
  f32x4 acc[4][2] = {};
  for (int k0 = 0; k0 < K; k0 += 64) {
    __syncthreads();
    *(u16x8*)&As[r0][ch0] = ra0;
    *(u16x8*)&As[r1][ch0] = ra1;
    *(u16x8*)&Bs[r0][ch0] = rb0;
    *(u16x8*)&Bs[r1][ch0] = rb1;
    __syncthreads();
    if (k0 + 64 < K) {
      ra0 = *(const u16x8*)(Arow0 + k0 + 64);
      ra1 = *(const u16x8*)(Arow1 + k0 + 64);
      rb0 = *(const u16x8*)(Brow0 + k0 + 64);
      rb1 = *(const u16x8*)(Brow1 + k0 + 64);
    }
#pragma unroll
    for (int ks = 0; ks < 2; ks++) {
      short8_t af[4], bf[2];
#pragma unroll
      for (int i = 0; i < 4; i++)
        af[i] = *(const short8_t*)&As[wm * 64 + i * 16 + l16][ks * 32 + g * 8];
#pragma unroll
      for (int j = 0; j < 2; j++)
        bf[j] = *(const short8_t*)&Bs[wn * 32 + j * 16 + l16][ks * 32 + g * 8];
#pragma unroll
      for (int mi = 0; mi < 4; mi++)
#pragma unroll
        for (int ni = 0; ni < 2; ni++)
          acc[mi][ni] = __builtin_amdgcn_mfma_f32_16x16x32_bf16(af[mi], bf[ni], acc[mi][ni], 0, 0, 0);
    }
  }
#pragma unroll
  for (int mi = 0; mi < 4; mi++) {
#pragma unroll
    for (int ni = 0; ni < 2; ni++) {
      int n = n0 + wn * 32 + ni * 16 + l16;
      float bv = 0.f;
      if (EPI != 0) bv = bias[n];
#pragma unroll
      for (int r = 0; r < 4; r++) {
        int m = m0 + wm * 64 + mi * 16 + g * 4 + r;
        float c = acc[mi][ni][r] + bv;
        if (EPI == 2) c += res[(size_t)m * N + n];
        if (EPI == 3) c = 0.5f * c * (1.f + erff(c * 0.70710678118f));
        if (OUTM & 1) Cf[(size_t)m * N + n] = c;
        if (OUTM & 2) Cb[(size_t)m * N + n] = f2bf(c);
      }
    }
  }
}

// ============ MHSA: swapped-QK MFMA flash, XCD-grouped grid, defer-max, cvt_pk P ============
__global__ __launch_bounds__(256) void k_attn_mfma(const unsigned short* __restrict__ qkv,
    unsigned short* __restrict__ o) {
  __shared__ unsigned short Ks[64][72];     // [key][dh]
  __shared__ unsigned short Vs[4608];       // subtiled, dd-stride 72, kk-stride 288
  __shared__ unsigned short Plb[4][16][72]; // per-wave P rows [q][k]
  // XCD-grouped mapping: all 16 qt-blocks of one (h,b) land on one XCD (round-robin id%8)
  int fid = blockIdx.x;
  int xcd = fid & 7, t = fid >> 3;
  int qt = t & 15;
  int hb = (t >> 4) * 8 + xcd;     // 0..47
  int h = hb % NHEAD, b = hb / NHEAD;
  int tid = threadIdx.x;
  int w = tid >> 6, lane = tid & 63;
  int g = lane >> 4, l16 = lane & 15;
  const unsigned short* base  = qkv + (size_t)b * Sc * E3;
  const unsigned short* kbase = base + Ec + h * 64;
  const unsigned short* vbase = base + 2 * Ec + h * 64;
  int q0 = qt * 64 + w * 16;

  // Q frags (B-operand), pre-scaled by pow2 1/8
  short8_t qf[2];
#pragma unroll
  for (int ks = 0; ks < 2; ks++) {
    short8_t f = *(const short8_t*)&base[(size_t)(q0 + l16) * E3 + h * 64 + ks * 32 + g * 8];
#pragma unroll
    for (int e = 0; e < 8; e++)
      f[e] = (short)f2bf(bf2f((unsigned short)f[e]) * 0.125f);
    qf[ks] = f;
  }

  // staging geometry
  int r0s = tid >> 3, ch0s = (tid & 7) * 8;
  int r1s = r0s + 32;
  int voff0 = (r0s >> 2) * 288 + (ch0s >> 4) * 72 + (r0s & 3) * 16 + ((ch0s >> 3) & 1) * 8;
  int voff1 = (r1s >> 2) * 288 + (ch0s >> 4) * 72 + (r1s & 3) * 16 + ((ch0s >> 3) & 1) * 8;
  const unsigned short* krow0 = kbase + (size_t)r0s * E3 + ch0s;
  const unsigned short* krow1 = kbase + (size_t)r1s * E3 + ch0s;
  const unsigned short* vrow0 = vbase + (size_t)r0s * E3 + ch0s;
  const unsigned short* vrow1 = vbase + (size_t)r1s * E3 + ch0s;
  constexpr size_t KTS = (size_t)64 * E3;

  u16x8 rk0 = *(const u16x8*)krow0;
  u16x8 rk1 = *(const u16x8*)krow1;
  u16x8 rv0 = *(const u16x8*)vrow0;
  u16x8 rv1 = *(const u16x8*)vrow1;

  f32x4 o_acc[4] = {};
  float m_r = -1e30f, l_r = 0.f;    // per-lane state for q-row = l16

  for (int kt = 0; kt < 16; kt++) {
    __syncthreads();
    *(u16x8*)&Ks[r0s][ch0s] = rk0;
    *(u16x8*)&Ks[r1s][ch0s] = rk1;
    *(u16x8*)&Vs[voff0] = rv0;
    *(u16x8*)&Vs[voff1] = rv1;
    __syncthreads();
    if (kt < 15) {
      size_t off = (size_t)(kt + 1) * KTS;
      rk0 = *(const u16x8*)(krow0 + off);
      rk1 = *(const u16x8*)(krow1 + off);
      rv0 = *(const u16x8*)(vrow0 + off);
      rv1 = *(const u16x8*)(vrow1 + off);
    }

    // S^T = K @ Q^T : row = k_local, col = q = l16
    f32x4 s_acc[4] = {};
#pragma unroll
    for (int nt = 0; nt < 4; nt++) {
#pragma unroll
      for (int ks = 0; ks < 2; ks++) {
        short8_t kf = *(const short8_t*)&Ks[nt * 16 + l16][ks * 32 + g * 8];
        s_acc[nt] = __builtin_amdgcn_mfma_f32_16x16x32_bf16(kf, qf[ks], s_acc[nt], 0, 0, 0);
      }
    }

    // tile max for q-row l16: 15 in-lane + 2 shfl
    float mx = s_acc[0][0];
#pragma unroll
    for (int nt = 0; nt < 4; nt++)
#pragma unroll
      for (int r = 0; r < 4; r++) mx = fmaxf(mx, s_acc[nt][r]);
    mx = fmaxf(mx, __shfl_xor(mx, 16));
    mx = fmaxf(mx, __shfl_xor(mx, 32));

    // defer-max (T13): only rescale when some row grew by > 8
    if (!__all(mx - m_r <= 8.f)) {
      float mn = fmaxf(m_r, mx);
      float sc = __expf(m_r - mn);
      m_r = mn;
      l_r *= sc;
      float osc[4];
#pragma unroll
      for (int r = 0; r < 4; r++) osc[r] = __shfl(sc, g * 4 + r);
#pragma unroll
      for (int dt = 0; dt < 4; dt++)
#pragma unroll
        for (int r = 0; r < 4; r++) o_acc[dt][r] *= osc[r];
    }

    float ts = 0.f;
#pragma unroll
    for (int nt = 0; nt < 4; nt++)
#pragma unroll
      for (int r = 0; r < 4; r++) {
        float pv = __expf(s_acc[nt][r] - m_r);
        s_acc[nt][r] = pv;
        ts += pv;
      }
    ts += __shfl_xor(ts, 16);
    ts += __shfl_xor(ts, 32);
    l_r += ts;

    // P^T -> Plb[q][k], single-instruction packed cvt per pair
#pragma unroll
    for (int nt = 0; nt < 4; nt++) {
      *(unsigned*)&Plb[w][l16][nt * 16 + g * 4] = cvtpk(s_acc[nt][0], s_acc[nt][1]);
      *(unsigned*)&Plb[w][l16][nt * 16 + g * 4 + 2] = cvtpk(s_acc[nt][2], s_acc[nt][3]);
    }

    // O += P @ V ; A-frag rows = q = l16, contiguous reads
#pragma unroll
    for (int ks = 0; ks < 2; ks++) {
      short8_t pf = *(const short8_t*)&Plb[w][l16][ks * 32 + g * 8];
      short4_t lo0, lo1, lo2, lo3, hi0, hi1, hi2, hi3;
      unsigned a0 = (unsigned)(uintptr_t)&Vs[(ks * 8 + g * 2) * 288 + 0 * 72 + l16] * 1u;
      unsigned a1 = a0 + 144, a2 = a0 + 288, a3 = a0 + 432;
      asm volatile("ds_read_b64_tr_b16 %0, %1" : "=v"(lo0) : "v"(a0));
      asm volatile("ds_read_b64_tr_b16 %0, %1 offset:576" : "=v"(hi0) : "v"(a0));
      asm volatile("ds_read_b64_tr_b16 %0, %1" : "=v"(lo1) : "v"(a1));
      asm volatile("ds_read_b64_tr_b16 %0, %1 offset:576" : "=v"(hi1) : "v"(a1));
      asm volatile("ds_read_b64_tr_b16 %0, %1" : "=v"(lo2) : "v"(a2));
      asm volatile("ds_read_b64_tr_b16 %0, %1 offset:576" : "=v"(hi2) : "v"(a2));
      asm volatile("ds_read_b64_tr_b16 %0, %1" : "=v"(lo3) : "v"(a3));
      asm volatile("ds_read_b64_tr_b16 %0, %1 offset:576" : "=v"(hi3) : "v"(a3));
      asm volatile("s_waitcnt lgkmcnt(0)");
      __builtin_amdgcn_sched_barrier(0);
      short4_t lo[4] = {lo0, lo1, lo2, lo3};
      short4_t hi[4] = {hi0, hi1, hi2, hi3};
#pragma unroll
      for (int dt = 0; dt < 4; dt++) {
        short8_t vf;
#pragma unroll
        for (int e = 0; e < 4; e++) { vf[e] = lo[dt][e]; vf[4 + e] = hi[dt][e]; }
        o_acc[dt] = __builtin_amdgcn_mfma_f32_16x16x32_bf16(pf, vf, o_acc[dt], 0, 0, 0);
      }
    }
  }

  // normalize: row q'=g*4+r uses l from lane q'
  float linv = 1.f / l_r;
  float inv4[4];
#pragma unroll
  for (int r = 0; r < 4; r++) inv4[r] = __shfl(linv, g * 4 + r);
  unsigned short* obase = o + (size_t)(b * Sc + q0) * Ec + h * 64;
#pragma unroll
  for (int r = 0; r < 4; r++) {
    int qrow = g * 4 + r;
#pragma unroll
    for (int dt = 0; dt < 4; dt++)
      obase[(size_t)qrow * Ec + dt * 16 + l16] = f2bf(o_acc[dt][r] * inv4[r]);
  }
}

// ============ LN over rows of E=768 (row-major outs) ============
template<int MODE>
__global__ __launch_bounds__(256) void k_lnrow(const float* __restrict__ in,
    const float* __restrict__ g, const float* __restrict__ bt,
    float* __restrict__ outf, unsigned short* __restrict__ outb) {
  int row = blockIdx.x;
  int tid = threadIdx.x;
  __shared__ float buf[Ec];
  __shared__ float rsum[4], rss[4];
  float sum = 0.f, ss = 0.f;
  for (int i = tid; i < Ec; i += 256) {
    float v = in[(size_t)row * Ec + i];
    buf[i] = v; sum += v; ss += v * v;
  }
#pragma unroll
  for (int off = 32; off > 0; off >>= 1) {
    sum += __shfl_xor(sum, off); ss += __shfl_xor(ss, off);
  }
  if ((tid & 63) == 0) { rsum[tid >> 6] = sum; rss[tid >> 6] = ss; }
  __syncthreads();
  sum = rsum[0] + rsum[1] + rsum[2] + rsum[3];
  ss = rss[0] + rss[1] + rss[2] + rss[3];
  float mean = sum / Ec;
  float rstd = rsqrtf(ss / Ec - mean * mean + 1e-5f);
  for (int i = tid; i < Ec; i += 256) {
    float v = (buf[i] - mean) * rstd * g[i] + bt[i];
    if (MODE == 2) outf[(size_t)row * Ec + i] = v;
    outb[(size_t)row * Ec + i] = f2bf(v);
  }
}

// ============ final LN: out = LN(n3+mlp) transposed to [B,E,H,W] ============
__global__ __launch_bounds__(256) void k_lnout(const float* __restrict__ in,
    const float* __restrict__ res, const float* __restrict__ g,
    const float* __restrict__ bt, float* __restrict__ out) {
  int r0 = blockIdx.x * 16;
  int b = r0 >> 10, s0 = r0 & 1023;
  __shared__ float Tr[16][772];
  __shared__ float mean_s[16], rstd_s[16];
  int rl = threadIdx.x >> 4, el = threadIdx.x & 15;
  const float* ip = in + (size_t)(r0 + rl) * Ec;
  const float* rp = res + (size_t)(r0 + rl) * Ec;
  float sum = 0.f, ss = 0.f;
  for (int i = el; i < Ec; i += 16) {
    float v = ip[i] + rp[i];
    Tr[rl][i] = v; sum += v; ss += v * v;
  }
#pragma unroll
  for (int off = 8; off; off >>= 1) {
    sum += __shfl_xor(sum, off); ss += __shfl_xor(ss, off);
  }
  if (el == 0) {
    float mean = sum / Ec;
    mean_s[rl] = mean;
    rstd_s[rl] = rsqrtf(ss / Ec - mean * mean + 1e-5f);
  }
  __syncthreads();
  int sl = threadIdx.x & 15, il = threadIdx.x >> 4;
  float mean = mean_s[sl], rstd = rstd_s[sl];
  for (int i = il; i < Ec; i += 16)
    out[((size_t)b * Ec + i) * Sc + s0 + sl] = (Tr[sl][i] - mean) * rstd * g[i] + bt[i];
}

// ============ per-node attention coefficients a_s, a_d (bf16 hN) ============
__global__ __launch_bounds__(256) void k_asd(const unsigned short* __restrict__ hNb,
    const float* __restrict__ att_src, const float* __restrict__ att_dst,
    float* __restrict__ a_s, float* __restrict__ a_d) {
  int n = blockIdx.x * 4 + (threadIdx.x >> 6);
  int lane = threadIdx.x & 63;
  const unsigned short* hrow = hNb + (size_t)n * Ec;
#pragma unroll
  for (int h = 0; h < GHEAD; h++) {
    float ps = 0.f, pd = 0.f;
    for (int d = lane; d < DGAT; d += 64) {
      float v = bf2f(hrow[h * DGAT + d]);
      ps += v * att_src[h * DGAT + d];
      pd += v * att_dst[h * DGAT + d];
    }
#pragma unroll
    for (int off = 32; off > 0; off >>= 1) {
      ps += __shfl_xor(ps, off); pd += __shfl_xor(pd, off);
    }
    if (lane == 0) { a_s[n * GHEAD + h] = ps; a_d[n * GHEAD + h] = pd; }
  }
}

// ============ GAT stencil (bf16 hN) ============
__global__ __launch_bounds__(256) void k_gat(const unsigned short* __restrict__ hNb,
    const float* __restrict__ a_s, const float* __restrict__ a_d,
    const float* __restrict__ x_attn, const float* __restrict__ gat_b,
    float* __restrict__ x_after) {
  int n = blockIdx.x;
  int b = n >> 10, s = n & 1023, r = s >> 5, c = s & 31;
  __shared__ int nbr[9];
  __shared__ float alpha[GHEAD][9];
  int tid = threadIdx.x;
  if (tid < 9) {
    int dr = tid / 3 - 1, dc = tid % 3 - 1;
    int rr = r + dr, cc = c + dc;
    int ok = (rr >= 0 && rr < 32 && cc >= 0 && cc < 32);
    if (dr == -1 && dc == 1 && cc == 31) ok = 0;
    if (dr == 1 && dc == -1 && c == 31) ok = 0;
    nbr[tid] = ok ? ((b << 10) + (rr << 5) + cc) : -1;
  }
  __syncthreads();
  if (tid < GHEAD) {
    int h = tid;
    float ad = a_d[n * GHEAD + h];
    float ev[9]; float m = -1e30f;
#pragma unroll
    for (int j = 0; j < 9; j++) {
      if (nbr[j] >= 0) {
        float e = a_s[nbr[j] * GHEAD + h] + ad;
        e = e > 0.f ? e : 0.2f * e;
        ev[j] = e; m = fmaxf(m, e);
      } else ev[j] = -1e30f;
    }
    float den = 0.f;
#pragma unroll
    for (int j = 0; j < 9; j++) {
      float x = (nbr[j] >= 0) ? expf(ev[j] - m) : 0.f;
      ev[j] = x; den += x;
    }
    float inv = 1.f / den;
#pragma unroll
    for (int j = 0; j < 9; j++) alpha[h][j] = ev[j] * inv;
  }
  __syncthreads();
  for (int e = tid; e < Ec; e += 256) {
    int h = e / DGAT;
    float acc = 0.f;
#pragma unroll
    for (int j = 0; j < 9; j++) {
      int nj = nbr[j];
      if (nj >= 0) acc += alpha[h][j] * bf2f(hNb[(size_t)nj * Ec + e]);
    }
    float v = acc + gat_b[e];
    v = v > 0.f ? v : expf(v) - 1.f;
    x_after[(size_t)n * Ec + e] = x_attn[(size_t)n * Ec + e] + v;
  }
}

extern "C" void kernel_launch(void* const* d_in, const int* in_sizes, int n_in,
                              void* d_out, int out_size, void* d_ws, size_t ws_size,
                              hipStream_t stream) {
  (void)in_sizes; (void)n_in; (void)out_size; (void)ws_size;
  const float* x      = (const float*)d_in[0];
  const float* ln1_g  = (const float*)d_in[1];
  const float* ln1_b  = (const float*)d_in[2];
  const float* proj_w = (const float*)d_in[3];
  const float* proj_b = (const float*)d_in[4];
  const float* wqkv   = (const float*)d_in[5];
  const float* bqkv   = (const float*)d_in[6];
  const float* wo     = (const float*)d_in[7];
  const float* bo     = (const float*)d_in[8];
  const float* ln2_g  = (const float*)d_in[9];
  const float* ln2_b  = (const float*)d_in[10];
  const float* gp_w   = (const float*)d_in[11];
  const float* gp_b   = (const float*)d_in[12];
  const float* gat_w  = (const float*)d_in[13];
  const float* att_src= (const float*)d_in[14];
  const float* att_dst= (const float*)d_in[15];
  const float* gat_b  = (const float*)d_in[16];
  const float* ln3_g  = (const float*)d_in[17];
  const float* ln3_b  = (const float*)d_in[18];
  const float* mlp_w1 = (const float*)d_in[19];
  const float* mlp_b1 = (const float*)d_in[20];
  const float* mlp_w2 = (const float*)d_in[21];
  const float* mlp_b2 = (const float*)d_in[22];
  const float* fn_g   = (const float*)d_in[23];
  const float* fn_b   = (const float*)d_in[24];
  float* out = (float*)d_out;

  // ---- workspace layout ----
  char* p = (char*)d_ws;
  auto alloc = [&](size_t bytes) { char* q = p; p += (bytes + 255) & ~(size_t)255; return q; };
  char* regA      = alloc((size_t)Ntok * E3 * 2);            // n1_bf -> qkv_bf
  unsigned short* n1_bf  = (unsigned short*)regA;
  unsigned short* qkv_bf = (unsigned short*)regA;
  unsigned short* proj_wt = (unsigned short*)alloc((size_t)Ec * Cc * 2);
  unsigned short* wqkv_t  = (unsigned short*)alloc((size_t)E3 * Ec * 2);
  unsigned short* wo_t    = (unsigned short*)alloc((size_t)Ec * Ec * 2);
  unsigned short* gp_bf   = (unsigned short*)alloc((size_t)Ec * Ec * 2);  // identity cast
  unsigned short* gat_t   = (unsigned short*)alloc((size_t)Ec * Ec * 2);
  unsigned short* m1_t    = (unsigned short*)alloc((size_t)Ec * Ec * 2);
  unsigned short* m2_t    = (unsigned short*)alloc((size_t)Ec * Ec * 2);
  unsigned short* gpgat_t = (unsigned short*)alloc((size_t)Ec * Ec * 2);  // (gp_w@gat_w)^T bf16
  float* bias2p = (float*)alloc((size_t)8 * Ec * 4);
  float* bias2  = (float*)alloc((size_t)Ec * 4);
  float* v_in   = (float*)alloc((size_t)Ntok * Ec * 4);
  unsigned short* v_in_bf = (unsigned short*)alloc((size_t)Ntok * Ec * 2);
  unsigned short* regE    = (unsigned short*)alloc((size_t)Ntok * Ec * 2); // o_bf -> h1_bf
  float* regF   = (float*)alloc((size_t)Ntok * Ec * 4);      // x_attn -> n3 f32
  unsigned short* regG    = (unsigned short*)alloc((size_t)Ntok * Ec * 2); // n2_bf -> n3_bf
  unsigned short* hN_bf   = (unsigned short*)alloc((size_t)Ntok * Ec * 2);
  float* regJ   = (float*)alloc((size_t)Ntok * Ec * 4);      // x_after -> mlp_out
  float* a_s    = (float*)alloc((size_t)Ntok * GHEAD * 4);
  float* a_d    = (float*)alloc((size_t)Ntok * GHEAD * 4);
  float* psum   = (float*)alloc((size_t)Ntok * 8 * 4);
  float* pss    = (float*)alloc((size_t)Ntok * 8 * 4);

  unsigned short* o_bf   = regE;
  unsigned short* h1_bf  = regE;
  float* x_attn = regF;
  float* n3_f   = regF;
  unsigned short* n2_bf  = regG;
  unsigned short* n3_bf  = regG;
  float* x_after = regJ;
  float* mlp_out = regJ;

  // 0) weights -> bf16 (6 transposed + gp identity)
  WtArgs wa;
  wa.src[0] = proj_w; wa.dst[0] = proj_wt; wa.K[0] = Cc; wa.N[0] = Ec;  wa.mode[0] = 0;
  wa.src[1] = wqkv;   wa.dst[1] = wqkv_t;  wa.K[1] = Ec; wa.N[1] = E3;  wa.mode[1] = 0;
  wa.src[2] = wo;     wa.dst[2] = wo_t;    wa.K[2] = Ec; wa.N[2] = Ec;  wa.mode[2] = 0;
  wa.src[3] = gat_w;  wa.dst[3] = gat_t;   wa.K[3] = Ec; wa.N[3] = Ec;  wa.mode[3] = 0;
  wa.src[4] = mlp_w1; wa.dst[4] = m1_t;    wa.K[4] = Ec; wa.N[4] = Ec;  wa.mode[4] = 0;
  wa.src[5] = mlp_w2; wa.dst[5] = m2_t;    wa.K[5] = Ec; wa.N[5] = Ec;  wa.mode[5] = 0;
  wa.src[6] = gp_w;   wa.dst[6] = gp_bf;   wa.K[6] = Ec; wa.N[6] = Ec;  wa.mode[6] = 1;
  int cum = 0;
  for (int i = 0; i < 7; i++) { wa.off[i] = cum; cum += (wa.K[i] >> 5) * (wa.N[i] >> 5); }
  wa.off[7] = cum;
  k_wt<<<cum, 256, 0, stream>>>(wa);

  // 0b) fused gp@gat weight + bias2 (parallel partials + reduce)
  k_bias2p<<<dim3(3, 8), 256, 0, stream>>>(gat_w, gp_b, bias2p);
  k_bias2r<<<3, 256, 0, stream>>>(bias2p, bias2);
  gemm_bf16<0, 2><<<dim3(Ec / 128, Ec / 128), 512, 0, stream>>>(
      gat_t, gp_bf, nullptr, nullptr, nullptr, gpgat_t, Ec, Ec, Ec);

  // 1) LN1 two-pass -> bf16 [M][C]
  k_ln1_stats<<<dim3(8, 64, 4), 256, 0, stream>>>(x, psum, pss);
  k_ln1_norm<<<dim3(16, 64, 4), 256, 0, stream>>>(x, ln1_g, ln1_b, psum, pss, n1_bf);
  // 2) v_in = n1 @ proj_w + proj_b  (f32 + bf16 out)
  gemm_bf16<1, 3><<<dim3(Ec / 128, Ntok / 128), 512, 0, stream>>>(
      n1_bf, proj_wt, proj_b, nullptr, v_in, v_in_bf, Ntok, Ec, Cc);
  // 3) qkv = v_in @ wqkv + bqkv  (bf16 out)
  gemm_bf16<1, 2><<<dim3(E3 / 128, Ntok / 128), 512, 0, stream>>>(
      v_in_bf, wqkv_t, bqkv, nullptr, nullptr, qkv_bf, Ntok, E3, Ec);
  // 4) attention (XCD-grouped 1D grid)
  k_attn_mfma<<<16 * NHEAD * Bc, 256, 0, stream>>>(qkv_bf, o_bf);
  // 5) x_attn = v_in + o @ wo + bo  (f32)
  gemm_bf16<2, 1><<<dim3(Ec / 128, Ntok / 128), 512, 0, stream>>>(
      o_bf, wo_t, bo, v_in, x_attn, nullptr, Ntok, Ec, Ec);
  // 6) n2 = LN(x_attn) -> bf16
  k_lnrow<0><<<Ntok, 256, 0, stream>>>(x_attn, ln2_g, ln2_b, nullptr, n2_bf);
  // 7+8 fused) hN = n2 @ (gp_w@gat_w) + gp_b@gat_w -> bf16
  gemm_bf16<1, 2><<<dim3(Ec / 128, Ntok / 128), 512, 0, stream>>>(
      n2_bf, gpgat_t, bias2, nullptr, nullptr, hN_bf, Ntok, Ec, Ec);
  // 9) a_s, a_d
  k_asd<<<Ntok / 4, 256, 0, stream>>>(hN_bf, att_src, att_dst, a_s, a_d);
  // 10) GAT aggregate + elu + residual -> x_after
  k_gat<<<Ntok, 256, 0, stream>>>(hN_bf, a_s, a_d, x_attn, gat_b, x_after);
  // 11) n3 = LN(x_after) -> f32 + bf16
  k_lnrow<2><<<Ntok, 256, 0, stream>>>(x_after, ln3_g, ln3_b, n3_f, n3_bf);
  // 12) h1 = gelu(n3 @ mlp_w1 + mlp_b1) -> bf16
  gemm_bf16<3, 2><<<dim3(Ec / 128, Ntok / 128), 512, 0, stream>>>(
      n3_bf, m1_t, mlp_b1, nullptr, nullptr, h1_bf, Ntok, Ec, Ec);
  // 13) mlp = h1 @ mlp_w2 + mlp_b2 -> f32
  gemm_bf16<1, 1><<<dim3(Ec / 128, Ntok / 128), 512, 0, stream>>>(
      h1_bf, m2_t, mlp_b2, nullptr, mlp_out, nullptr, Ntok, Ec, Ec);
  // 14) out = LN(n3 + mlp), transposed to [B,E,H,W]
  k_lnout<<<256, 256, 0, stream>>>(n3_f, mlp_out, fn_g, fn_b, out);
}

// Round 10
// 253.907 us; speedup vs baseline: 1.1219x; 1.0091x over previous
//
#include <hip/hip_runtime.h>

// ---- problem constants ----
constexpr int Bc = 4;
constexpr int Cc = 2048;
constexpr int Sc = 1024;     // H*W = 32*32
constexpr int Ntok = 4096;   // B*S
constexpr int Ec = 768;
constexpr int E3 = 2304;
constexpr int NHEAD = 12;
constexpr int GHEAD = 4;
constexpr int DGAT = 192;

typedef __attribute__((ext_vector_type(8))) short short8_t;   // bf16x8 MFMA frag
typedef __attribute__((ext_vector_type(4))) short short4_t;
typedef __attribute__((ext_vector_type(8))) unsigned short u16x8;
typedef __attribute__((ext_vector_type(4))) float f32x4;

// software RNE f32->bf16
__device__ inline unsigned short f2bf(float f) {
  unsigned int u = __builtin_bit_cast(unsigned int, f);
  u += 0x7FFFu + ((u >> 16) & 1u);
  return (unsigned short)(u >> 16);
}
__device__ inline float bf2f(unsigned short h) {
  unsigned int u = ((unsigned int)h) << 16;
  return __builtin_bit_cast(float, u);
}
// packed hw cvt (P fragments only; verified absmax-neutral)
__device__ inline unsigned cvtpk(float lo, float hi) {
  unsigned r;
  asm("v_cvt_pk_bf16_f32 %0, %1, %2" : "=v"(r) : "v"(lo), "v"(hi));
  return r;
}

// ============ weight prep: 6 transposed + 1 identity bf16 cast ============
struct WtArgs {
  const float* src[7];
  unsigned short* dst[7];
  int K[7], N[7], mode[7];
  int off[8];
};
__global__ __launch_bounds__(256) void k_wt(WtArgs a) {
  __shared__ float t[32][33];
  int bid = blockIdx.x;
  int w = 0;
  while (w < 6 && bid >= a.off[w + 1]) ++w;
  int local = bid - a.off[w];
  int K = a.K[w], N = a.N[w];
  int ntn = N >> 5;
  int tk = local / ntn, tn = local - tk * ntn;
  int k0 = tk * 32, n0 = tn * 32;
  int tx = threadIdx.x & 31, ty = threadIdx.x >> 5;
  const float* src = a.src[w];
  unsigned short* dst = a.dst[w];
  if (a.mode[w]) {
#pragma unroll
    for (int i = 0; i < 4; i++)
      dst[(size_t)(k0 + ty + i * 8) * N + n0 + tx] =
          f2bf(src[(size_t)(k0 + ty + i * 8) * N + n0 + tx]);
    return;
  }
#pragma unroll
  for (int i = 0; i < 4; i++)
    t[ty + i * 8][tx] = src[(size_t)(k0 + ty + i * 8) * N + n0 + tx];
  __syncthreads();
#pragma unroll
  for (int i = 0; i < 4; i++)
    dst[(size_t)(n0 + ty + i * 8) * K + k0 + tx] = f2bf(t[tx][ty + i * 8]);
}

// ============ bias2 = gp_b @ gat_w: parallel partials (3x8 grid) + reduce ============
__global__ __launch_bounds__(256) void k_bias2p(const float* __restrict__ gat_w,
    const float* __restrict__ gp_b, float* __restrict__ part) {
  int m = blockIdx.x * 256 + threadIdx.x;
  int jc = blockIdx.y;
  float acc = 0.f;
#pragma unroll 8
  for (int j = jc * 96; j < jc * 96 + 96; j++)
    acc += gp_b[j] * gat_w[(size_t)j * Ec + m];
  part[jc * Ec + m] = acc;
}
__global__ __launch_bounds__(256) void k_bias2r(const float* __restrict__ part,
    float* __restrict__ bias2) {
  int m = blockIdx.x * 256 + threadIdx.x;
  float acc = 0.f;
#pragma unroll
  for (int j = 0; j < 8; j++) acc += part[j * Ec + m];
  bias2[m] = acc;
}

// ============ LN1 pass A ============
__global__ __launch_bounds__(256) void k_ln1_stats(const float* __restrict__ x,
    float* __restrict__ psum, float* __restrict__ pss) {
  int cc = blockIdx.x, st = blockIdx.y, b = blockIdx.z;
  int sl = threadIdx.x & 15, cl = threadIdx.x >> 4;
  int s = st * 16 + sl;
  const float* xb = x + (size_t)b * Cc * Sc + s;
  float sum = 0.f, ss = 0.f;
#pragma unroll
  for (int t = 0; t < 16; t++) {
    int c = cc * 256 + cl + t * 16;
    float v = xb[(size_t)c * Sc];
    sum += v; ss += v * v;
  }
  __shared__ float rs0[16][17], rs1[16][17];
  rs0[cl][sl] = sum; rs1[cl][sl] = ss;
  __syncthreads();
  if (cl == 0) {
    float a = 0.f, q = 0.f;
#pragma unroll
    for (int i = 0; i < 16; i++) { a += rs0[i][sl]; q += rs1[i][sl]; }
    size_t bs = (size_t)(b * Sc + st * 16 + sl);
    psum[bs * 8 + cc] = a;
    pss[bs * 8 + cc] = q;
  }
}

// ============ LN1 pass B ============
__global__ __launch_bounds__(256) void k_ln1_norm(const float* __restrict__ x,
    const float* __restrict__ g, const float* __restrict__ bt,
    const float* __restrict__ psum, const float* __restrict__ pss,
    unsigned short* __restrict__ out) {
  int cc = blockIdx.x, st = blockIdx.y, b = blockIdx.z;
  int sl = threadIdx.x & 15, cl = threadIdx.x >> 4;
  int s = st * 16 + sl;
  __shared__ float red[16][17];
  __shared__ float mean_s[16], rstd_s[16];
  int t8 = cl;
  size_t bsrow = (size_t)(b * Sc + st * 16 + sl);
  float v = (t8 < 8) ? psum[bsrow * 8 + t8] : pss[bsrow * 8 + (t8 - 8)];
  red[t8][sl] = v;
  __syncthreads();
  if (threadIdx.x < 16) {
    float s0 = 0.f, s1 = 0.f;
#pragma unroll
    for (int i = 0; i < 8; i++) { s0 += red[i][threadIdx.x]; s1 += red[i + 8][threadIdx.x]; }
    float mean = s0 / Cc;
    mean_s[threadIdx.x] = mean;
    rstd_s[threadIdx.x] = rsqrtf(s1 / Cc - mean * mean + 1e-5f);
  }
  __syncthreads();
  float mean = mean_s[sl], rstd = rstd_s[sl];
  const float* xb = x + (size_t)b * Cc * Sc + s;
  __shared__ unsigned short Tc[16][136];
  int cb = cc * 128;
#pragma unroll
  for (int t = 0; t < 8; t++) {
    int c = cb + cl + t * 16;
    float xv = xb[(size_t)c * Sc];
    Tc[sl][cl + t * 16] = f2bf((xv - mean) * rstd * g[c] + bt[c]);
  }
  __syncthreads();
  int rl = threadIdx.x >> 4, el = threadIdx.x & 15;
  unsigned short* ob = out + ((size_t)(b * Sc) + st * 16 + rl) * Cc + cb;
  *(u16x8*)&ob[el * 8] = *(const u16x8*)&Tc[rl][el * 8];
}

// ============ bf16 MFMA GEMM, 128x128 tile, 512 thr, reg-dbuf (for qkv) ============
template<int EPI, int OUTM>
__global__ __launch_bounds__(512) void gemm_bf16(
    const unsigned short* __restrict__ A, const unsigned short* __restrict__ Bt,
    const float* __restrict__ bias, const float* __restrict__ res,
    float* __restrict__ Cf, unsigned short* __restrict__ Cb,
    int M, int N, int K) {
  __shared__ unsigned short As[128][72];
  __shared__ unsigned short Bs[128][72];
  int tid = threadIdx.x;
  int w = tid >> 6, lane = tid & 63, g = lane >> 4, l16 = lane & 15;
  int wm = w >> 2, wn = w & 3;
  int m0 = blockIdx.y * 128, n0 = blockIdx.x * 128;
  int r0 = tid >> 3, ch0 = (tid & 7) * 8;
  int r1 = r0 + 64;
  const unsigned short* Arow0 = A + (size_t)(m0 + r0) * K + ch0;
  const unsigned short* Arow1 = A + (size_t)(m0 + r1) * K + ch0;
  const unsigned short* Brow0 = Bt + (size_t)(n0 + r0) * K + ch0;
  const unsigned short* Brow1 = Bt + (size_t)(n0 + r1) * K + ch0;
  u16x8 ra0 = *(const u16x8*)Arow0;
  u16x8 ra1 = *(const u16x8*)Arow1;
  u16x8 rb0 = *(const u16x8*)Brow0;
  u16x8 rb1 = *(const u16x8*)Brow1;
  f32x4 acc[4][2] = {};
  for (int k0 = 0; k0 < K; k0 += 64) {
    __syncthreads();
    *(u16x8*)&As[r0][ch0] = ra0;
    *(u16x8*)&As[r1][ch0] = ra1;
    *(u16x8*)&Bs[r0][ch0] = rb0;
    *(u16x8*)&Bs[r1][ch0] = rb1;
    __syncthreads();
    if (k0 + 64 < K) {
      ra0 = *(const u16x8*)(Arow0 + k0 + 64);
      ra1 = *(const u16x8*)(Arow1 + k0 + 64);
      rb0 = *(const u16x8*)(Brow0 + k0 + 64);
      rb1 = *(const u16x8*)(Brow1 + k0 + 64);
    }
#pragma unroll
    for (int ks = 0; ks < 2; ks++) {
      short8_t af[4], bf[2];
#pragma unroll
      for (int i = 0; i < 4; i++)
        af[i] = *(const short8_t*)&As[wm * 64 + i * 16 + l16][ks * 32 + g * 8];
#pragma unroll
      for (int j = 0; j < 2; j++)
        bf[j] = *(const short8_t*)&Bs[wn * 32 + j * 16 + l16][ks * 32 + g * 8];
#pragma unroll
      for (int mi = 0; mi < 4; mi++)
#pragma unroll
        for (int ni = 0; ni < 2; ni++)
          acc[mi][ni] = __builtin_amdgcn_mfma_f32_16x16x32_bf16(af[mi], bf[ni], acc[mi][ni], 0, 0, 0);
    }
  }
#pragma unroll
  for (int mi = 0; mi < 4; mi++) {
#pragma unroll
    for (int ni = 0; ni < 2; ni++) {
      int n = n0 + wn * 32 + ni * 16 + l16;
      float bv = 0.f;
      if (EPI != 0) bv = bias[n];
#pragma unroll
      for (int r = 0; r < 4; r++) {
        int m = m0 + wm * 64 + mi * 16 + g * 4 + r;
        float c = acc[mi][ni][r] + bv;
        if (EPI == 2) c += res[(size_t)m * N + n];
        if (EPI == 3) c = 0.5f * c * (1.f + erff(c * 0.70710678118f));
        if (OUTM & 1) Cf[(size_t)m * N + n] = c;
        if (OUTM & 2) Cb[(size_t)m * N + n] = f2bf(c);
      }
    }
  }
}

// ============ bf16 MFMA GEMM, 64x128 tile, 256 thr = 4 waves (2Mx2N), reg-dbuf ============
// Doubles grid occupancy for M=4096,N=768 shapes (384 blocks vs 192).
template<int EPI, int OUTM>
__global__ __launch_bounds__(256) void gemm64_bf16(
    const unsigned short* __restrict__ A, const unsigned short* __restrict__ Bt,
    const float* __restrict__ bias, const float* __restrict__ res,
    float* __restrict__ Cf, unsigned short* __restrict__ Cb,
    int M, int N, int K) {
  __shared__ unsigned short As[64][72];
  __shared__ unsigned short Bs[128][72];
  int tid = threadIdx.x;
  int w = tid >> 6, lane = tid & 63, g = lane >> 4, l16 = lane & 15;
  int wm = w >> 1, wn = w & 1;           // wave tile 32M x 64N
  int m0 = blockIdx.y * 64, n0 = blockIdx.x * 128;
  int r0 = tid >> 3, ch0 = (tid & 7) * 8;   // r0: 0..31
  const unsigned short* ArowA = A + (size_t)(m0 + r0) * K + ch0;
  const unsigned short* ArowB = A + (size_t)(m0 + r0 + 32) * K + ch0;
  const unsigned short* Brow0 = Bt + (size_t)(n0 + r0) * K + ch0;
  const unsigned short* Brow1 = Bt + (size_t)(n0 + r0 + 32) * K + ch0;
  const unsigned short* Brow2 = Bt + (size_t)(n0 + r0 + 64) * K + ch0;
  const unsigned short* Brow3 = Bt + (size_t)(n0 + r0 + 96) * K + ch0;
  u16x8 raA = *(const u16x8*)ArowA;
  u16x8 raB = *(const u16x8*)ArowB;
  u16x8 rb0 = *(const u16x8*)Brow0;
  u16x8 rb1 = *(const u16x8*)Brow1;
  u16x8 rb2 = *(const u16x8*)Brow2;
  u16x8 rb3 = *(const u16x8*)Brow3;
  f32x4 acc[2][4] = {};
  for (int k0 = 0; k0 < K; k0 += 64) {
    __syncthreads();
    *(u16x8*)&As[r0][ch0] = raA;
    *(u16x8*)&As[r0 + 32][ch0] = raB;
    *(u16x8*)&Bs[r0][ch0] = rb0;
    *(u16x8*)&Bs[r0 + 32][ch0] = rb1;
    *(u16x8*)&Bs[r0 + 64][ch0] = rb2;
    *(u16x8*)&Bs[r0 + 96][ch0] = rb3;
    __syncthreads();
    if (k0 + 64 < K) {
      raA = *(const u16x8*)(ArowA + k0 + 64);
      raB = *(const u16x8*)(ArowB + k0 + 64);
      rb0 = *(const u16x8*)(Brow0 + k0 + 64);
      rb1 = *(const u16x8*)(Brow1 + k0 + 64);
      rb2 = *(const u16x8*)(Brow2 + k0 + 64);
      rb3 = *(const u16x8*)(Brow3 + k0 + 64);
    }
#pragma unroll
    for (int ks = 0; ks < 2; ks++) {
      short8_t af[2], bf[4];
#pragma unroll
      for (int i = 0; i < 2; i++)
        af[i] = *(const short8_t*)&As[wm * 32 + i * 16 + l16][ks * 32 + g * 8];
#pragma unroll
      for (int j = 0; j < 4; j++)
        bf[j] = *(const short8_t*)&Bs[wn * 64 + j * 16 + l16][ks * 32 + g * 8];
#pragma unroll
      for (int mi = 0; mi < 2; mi++)
#pragma unroll
        for (int ni = 0; ni < 4; ni++)
          acc[mi][ni] = __builtin_amdgcn_mfma_f32_16x16x32_bf16(af[mi], bf[ni], acc[mi][ni], 0, 0, 0);
    }
  }
#pragma unroll
  for (int mi = 0; mi < 2; mi++) {
#pragma unroll
    for (int ni = 0; ni < 4; ni++) {
      int n = n0 + wn * 64 + ni * 16 + l16;
      float bv = 0.f;
      if (EPI != 0) bv = bias[n];
#pragma unroll
      for (int r = 0; r < 4; r++) {
        int m = m0 + wm * 32 + mi * 16 + g * 4 + r;
        float c = acc[mi][ni][r] + bv;
        if (EPI == 2) c += res[(size_t)m * N + n];
        if (EPI == 3) c = 0.5f * c * (1.f + erff(c * 0.70710678118f));
        if (OUTM & 1) Cf[(size_t)m * N + n] = c;
        if (OUTM & 2) Cb[(size_t)m * N + n] = f2bf(c);
      }
    }
  }
}

// ============ MHSA: swapped-QK MFMA flash, XCD-grouped grid, defer-max, cvt_pk P ============
__global__ __launch_bounds__(256) void k_attn_mfma(const unsigned short* __restrict__ qkv,
    unsigned short* __restrict__ o) {
  __shared__ unsigned short Ks[64][72];
  __shared__ unsigned short Vs[4608];
  __shared__ unsigned short Plb[4][16][72];
  int fid = blockIdx.x;
  int xcd = fid & 7, t = fid >> 3;
  int qt = t & 15;
  int hb = (t >> 4) * 8 + xcd;
  int h = hb % NHEAD, b = hb / NHEAD;
  int tid = threadIdx.x;
  int w = tid >> 6, lane = tid & 63;
  int g = lane >> 4, l16 = lane & 15;
  const unsigned short* base  = qkv + (size_t)b * Sc * E3;
  const unsigned short* kbase = base + Ec + h * 64;
  const unsigned short* vbase = base + 2 * Ec + h * 64;
  int q0 = qt * 64 + w * 16;

  short8_t qf[2];
#pragma unroll
  for (int ks = 0; ks < 2; ks++) {
    short8_t f = *(const short8_t*)&base[(size_t)(q0 + l16) * E3 + h * 64 + ks * 32 + g * 8];
#pragma unroll
    for (int e = 0; e < 8; e++)
      f[e] = (short)f2bf(bf2f((unsigned short)f[e]) * 0.125f);
    qf[ks] = f;
  }

  int r0s = tid >> 3, ch0s = (tid & 7) * 8;
  int r1s = r0s + 32;
  int voff0 = (r0s >> 2) * 288 + (ch0s >> 4) * 72 + (r0s & 3) * 16 + ((ch0s >> 3) & 1) * 8;
  int voff1 = (r1s >> 2) * 288 + (ch0s >> 4) * 72 + (r1s & 3) * 16 + ((ch0s >> 3) & 1) * 8;
  const unsigned short* krow0 = kbase + (size_t)r0s * E3 + ch0s;
  const unsigned short* krow1 = kbase + (size_t)r1s * E3 + ch0s;
  const unsigned short* vrow0 = vbase + (size_t)r0s * E3 + ch0s;
  const unsigned short* vrow1 = vbase + (size_t)r1s * E3 + ch0s;
  constexpr size_t KTS = (size_t)64 * E3;

  u16x8 rk0 = *(const u16x8*)krow0;
  u16x8 rk1 = *(const u16x8*)krow1;
  u16x8 rv0 = *(const u16x8*)vrow0;
  u16x8 rv1 = *(const u16x8*)vrow1;

  f32x4 o_acc[4] = {};
  float m_r = -1e30f, l_r = 0.f;

  for (int kt = 0; kt < 16; kt++) {
    __syncthreads();
    *(u16x8*)&Ks[r0s][ch0s] = rk0;
    *(u16x8*)&Ks[r1s][ch0s] = rk1;
    *(u16x8*)&Vs[voff0] = rv0;
    *(u16x8*)&Vs[voff1] = rv1;
    __syncthreads();
    if (kt < 15) {
      size_t off = (size_t)(kt + 1) * KTS;
      rk0 = *(const u16x8*)(krow0 + off);
      rk1 = *(const u16x8*)(krow1 + off);
      rv0 = *(const u16x8*)(vrow0 + off);
      rv1 = *(const u16x8*)(vrow1 + off);
    }

    f32x4 s_acc[4] = {};
#pragma unroll
    for (int nt = 0; nt < 4; nt++) {
#pragma unroll
      for (int ks = 0; ks < 2; ks++) {
        short8_t kf = *(const short8_t*)&Ks[nt * 16 + l16][ks * 32 + g * 8];
        s_acc[nt] = __builtin_amdgcn_mfma_f32_16x16x32_bf16(kf, qf[ks], s_acc[nt], 0, 0, 0);
      }
    }

    float mx = s_acc[0][0];
#pragma unroll
    for (int nt = 0; nt < 4; nt++)
#pragma unroll
      for (int r = 0; r < 4; r++) mx = fmaxf(mx, s_acc[nt][r]);
    mx = fmaxf(mx, __shfl_xor(mx, 16));
    mx = fmaxf(mx, __shfl_xor(mx, 32));

    if (!__all(mx - m_r <= 8.f)) {
      float mn = fmaxf(m_r, mx);
      float sc = __expf(m_r - mn);
      m_r = mn;
      l_r *= sc;
      float osc[4];
#pragma unroll
      for (int r = 0; r < 4; r++) osc[r] = __shfl(sc, g * 4 + r);
#pragma unroll
      for (int dt = 0; dt < 4; dt++)
#pragma unroll
        for (int r = 0; r < 4; r++) o_acc[dt][r] *= osc[r];
    }

    float ts = 0.f;
#pragma unroll
    for (int nt = 0; nt < 4; nt++)
#pragma unroll
      for (int r = 0; r < 4; r++) {
        float pv = __expf(s_acc[nt][r] - m_r);
        s_acc[nt][r] = pv;
        ts += pv;
      }
    ts += __shfl_xor(ts, 16);
    ts += __shfl_xor(ts, 32);
    l_r += ts;

#pragma unroll
    for (int nt = 0; nt < 4; nt++) {
      *(unsigned*)&Plb[w][l16][nt * 16 + g * 4] = cvtpk(s_acc[nt][0], s_acc[nt][1]);
      *(unsigned*)&Plb[w][l16][nt * 16 + g * 4 + 2] = cvtpk(s_acc[nt][2], s_acc[nt][3]);
    }

#pragma unroll
    for (int ks = 0; ks < 2; ks++) {
      short8_t pf = *(const short8_t*)&Plb[w][l16][ks * 32 + g * 8];
      short4_t lo0, lo1, lo2, lo3, hi0, hi1, hi2, hi3;
      unsigned a0 = (unsigned)(uintptr_t)&Vs[(ks * 8 + g * 2) * 288 + 0 * 72 + l16] * 1u;
      unsigned a1 = a0 + 144, a2 = a0 + 288, a3 = a0 + 432;
      asm volatile("ds_read_b64_tr_b16 %0, %1" : "=v"(lo0) : "v"(a0));
      asm volatile("ds_read_b64_tr_b16 %0, %1 offset:576" : "=v"(hi0) : "v"(a0));
      asm volatile("ds_read_b64_tr_b16 %0, %1" : "=v"(lo1) : "v"(a1));
      asm volatile("ds_read_b64_tr_b16 %0, %1 offset:576" : "=v"(hi1) : "v"(a1));
      asm volatile("ds_read_b64_tr_b16 %0, %1" : "=v"(lo2) : "v"(a2));
      asm volatile("ds_read_b64_tr_b16 %0, %1 offset:576" : "=v"(hi2) : "v"(a2));
      asm volatile("ds_read_b64_tr_b16 %0, %1" : "=v"(lo3) : "v"(a3));
      asm volatile("ds_read_b64_tr_b16 %0, %1 offset:576" : "=v"(hi3) : "v"(a3));
      asm volatile("s_waitcnt lgkmcnt(0)");
      __builtin_amdgcn_sched_barrier(0);
      short4_t lo[4] = {lo0, lo1, lo2, lo3};
      short4_t hi[4] = {hi0, hi1, hi2, hi3};
#pragma unroll
      for (int dt = 0; dt < 4; dt++) {
        short8_t vf;
#pragma unroll
        for (int e = 0; e < 4; e++) { vf[e] = lo[dt][e]; vf[4 + e] = hi[dt][e]; }
        o_acc[dt] = __builtin_amdgcn_mfma_f32_16x16x32_bf16(pf, vf, o_acc[dt], 0, 0, 0);
      }
    }
  }

  float linv = 1.f / l_r;
  float inv4[4];
#pragma unroll
  for (int r = 0; r < 4; r++) inv4[r] = __shfl(linv, g * 4 + r);
  unsigned short* obase = o + (size_t)(b * Sc + q0) * Ec + h * 64;
#pragma unroll
  for (int r = 0; r < 4; r++) {
    int qrow = g * 4 + r;
#pragma unroll
    for (int dt = 0; dt < 4; dt++)
      obase[(size_t)qrow * Ec + dt * 16 + l16] = f2bf(o_acc[dt][r] * inv4[r]);
  }
}

// ============ LN over rows of E=768 ============
template<int MODE>
__global__ __launch_bounds__(256) void k_lnrow(const float* __restrict__ in,
    const float* __restrict__ g, const float* __restrict__ bt,
    float* __restrict__ outf, unsigned short* __restrict__ outb) {
  int row = blockIdx.x;
  int tid = threadIdx.x;
  __shared__ float buf[Ec];
  __shared__ float rsum[4], rss[4];
  float sum = 0.f, ss = 0.f;
  for (int i = tid; i < Ec; i += 256) {
    float v = in[(size_t)row * Ec + i];
    buf[i] = v; sum += v; ss += v * v;
  }
#pragma unroll
  for (int off = 32; off > 0; off >>= 1) {
    sum += __shfl_xor(sum, off); ss += __shfl_xor(ss, off);
  }
  if ((tid & 63) == 0) { rsum[tid >> 6] = sum; rss[tid >> 6] = ss; }
  __syncthreads();
  sum = rsum[0] + rsum[1] + rsum[2] + rsum[3];
  ss = rss[0] + rss[1] + rss[2] + rss[3];
  float mean = sum / Ec;
  float rstd = rsqrtf(ss / Ec - mean * mean + 1e-5f);
  for (int i = tid; i < Ec; i += 256) {
    float v = (buf[i] - mean) * rstd * g[i] + bt[i];
    if (MODE == 2) outf[(size_t)row * Ec + i] = v;
    outb[(size_t)row * Ec + i] = f2bf(v);
  }
}

// ============ final LN ============
__global__ __launch_bounds__(256) void k_lnout(const float* __restrict__ in,
    const float* __restrict__ res, const float* __restrict__ g,
    const float* __restrict__ bt, float* __restrict__ out) {
  int r0 = blockIdx.x * 16;
  int b = r0 >> 10, s0 = r0 & 1023;
  __shared__ float Tr[16][772];
  __shared__ float mean_s[16], rstd_s[16];
  int rl = threadIdx.x >> 4, el = threadIdx.x & 15;
  const float* ip = in + (size_t)(r0 + rl) * Ec;
  const float* rp = res + (size_t)(r0 + rl) * Ec;
  float sum = 0.f, ss = 0.f;
  for (int i = el; i < Ec; i += 16) {
    float v = ip[i] + rp[i];
    Tr[rl][i] = v; sum += v; ss += v * v;
  }
#pragma unroll
  for (int off = 8; off; off >>= 1) {
    sum += __shfl_xor(sum, off); ss += __shfl_xor(ss, off);
  }
  if (el == 0) {
    float mean = sum / Ec;
    mean_s[rl] = mean;
    rstd_s[rl] = rsqrtf(ss / Ec - mean * mean + 1e-5f);
  }
  __syncthreads();
  int sl = threadIdx.x & 15, il = threadIdx.x >> 4;
  float mean = mean_s[sl], rstd = rstd_s[sl];
  for (int i = il; i < Ec; i += 16)
    out[((size_t)b * Ec + i) * Sc + s0 + sl] = (Tr[sl][i] - mean) * rstd * g[i] + bt[i];
}

// ============ fused GAT: stage 9 nbr rows in LDS, a_s/a_d dots, softmax, aggregate ============
__global__ __launch_bounds__(256) void k_gatfull(const unsigned short* __restrict__ hNb,
    const float* __restrict__ att_src, const float* __restrict__ att_dst,
    const float* __restrict__ x_attn, const float* __restrict__ gat_b,
    float* __restrict__ x_after) {
  int n = blockIdx.x;
  int b = n >> 10, s = n & 1023, r = s >> 5, c = s & 31;
  __shared__ int nbr[9];
  __shared__ unsigned short hrows[9][Ec];   // 13.8KB
  __shared__ float alpha[GHEAD][9];
  int tid = threadIdx.x;
  if (tid < 9) {
    int dr = tid / 3 - 1, dc = tid % 3 - 1;
    int rr = r + dr, cc = c + dc;
    int ok = (rr >= 0 && rr < 32 && cc >= 0 && cc < 32);
    if (dr == -1 && dc == 1 && cc == 31) ok = 0;
    if (dr == 1 && dc == -1 && c == 31) ok = 0;
    nbr[tid] = ok ? ((b << 10) + (rr << 5) + cc) : -1;
  }
  __syncthreads();
  // stage valid neighbor rows (u16x8-coalesced)
  for (int i = tid; i < 9 * 96; i += 256) {
    int j = i / 96, e8 = i - j * 96;
    if (nbr[j] >= 0)
      *(u16x8*)&hrows[j][e8 * 8] = *(const u16x8*)&hNb[(size_t)nbr[j] * Ec + e8 * 8];
  }
  __syncthreads();
  // per-wave head: a_s dots for 9 nbrs + a_d(self), 64-lane reduce (3 els/lane over 192)
  int w = tid >> 6, lane = tid & 63;
  {
    float pd = 0.f;
#pragma unroll
    for (int t = 0; t < 3; t++) {
      int d = w * DGAT + lane + t * 64;
      pd += bf2f(hrows[4][d]) * att_dst[d];
    }
#pragma unroll
    for (int off = 32; off; off >>= 1) pd += __shfl_xor(pd, off);
    float as_j[9];
#pragma unroll
    for (int j = 0; j < 9; j++) {
      float p = 0.f;
      if (nbr[j] >= 0) {
#pragma unroll
        for (int t = 0; t < 3; t++) {
          int d = w * DGAT + lane + t * 64;
          p += bf2f(hrows[j][d]) * att_src[d];
        }
      }
#pragma unroll
      for (int off = 32; off; off >>= 1) p += __shfl_xor(p, off);
      as_j[j] = p;
    }
    if (lane == 0) {
      float ev[9]; float m = -1e30f;
#pragma unroll
      for (int j = 0; j < 9; j++) {
        if (nbr[j] >= 0) {
          float e = as_j[j] + pd;
          e = e > 0.f ? e : 0.2f * e;
          ev[j] = e; m = fmaxf(m, e);
        } else ev[j] = -1e30f;
      }
      float den = 0.f;
#pragma unroll
      for (int j = 0; j < 9; j++) {
        float xv = (nbr[j] >= 0) ? expf(ev[j] - m) : 0.f;
        ev[j] = xv; den += xv;
      }
      float inv = 1.f / den;
#pragma unroll
      for (int j = 0; j < 9; j++) alpha[w][j] = ev[j] * inv;
    }
  }
  __syncthreads();
  // aggregate from LDS + elu + residual
  for (int e = tid; e < Ec; e += 256) {
    int h = e / DGAT;
    float acc = 0.f;
#pragma unroll
    for (int j = 0; j < 9; j++) {
      if (nbr[j] >= 0) acc += alpha[h][j] * bf2f(hrows[j][e]);
    }
    float v = acc + gat_b[e];
    v = v > 0.f ? v : expf(v) - 1.f;
    x_after[(size_t)n * Ec + e] = x_attn[(size_t)n * Ec + e] + v;
  }
}

extern "C" void kernel_launch(void* const* d_in, const int* in_sizes, int n_in,
                              void* d_out, int out_size, void* d_ws, size_t ws_size,
                              hipStream_t stream) {
  (void)in_sizes; (void)n_in; (void)out_size; (void)ws_size;
  const float* x      = (const float*)d_in[0];
  const float* ln1_g  = (const float*)d_in[1];
  const float* ln1_b  = (const float*)d_in[2];
  const float* proj_w = (const float*)d_in[3];
  const float* proj_b = (const float*)d_in[4];
  const float* wqkv   = (const float*)d_in[5];
  const float* bqkv   = (const float*)d_in[6];
  const float* wo     = (const float*)d_in[7];
  const float* bo     = (const float*)d_in[8];
  const float* ln2_g  = (const float*)d_in[9];
  const float* ln2_b  = (const float*)d_in[10];
  const float* gp_w   = (const float*)d_in[11];
  const float* gp_b   = (const float*)d_in[12];
  const float* gat_w  = (const float*)d_in[13];
  const float* att_src= (const float*)d_in[14];
  const float* att_dst= (const float*)d_in[15];
  const float* gat_b  = (const float*)d_in[16];
  const float* ln3_g  = (const float*)d_in[17];
  const float* ln3_b  = (const float*)d_in[18];
  const float* mlp_w1 = (const float*)d_in[19];
  const float* mlp_b1 = (const float*)d_in[20];
  const float* mlp_w2 = (const float*)d_in[21];
  const float* mlp_b2 = (const float*)d_in[22];
  const float* fn_g   = (const float*)d_in[23];
  const float* fn_b   = (const float*)d_in[24];
  float* out = (float*)d_out;

  // ---- workspace layout ----
  char* p = (char*)d_ws;
  auto alloc = [&](size_t bytes) { char* q = p; p += (bytes + 255) & ~(size_t)255; return q; };
  char* regA      = alloc((size_t)Ntok * E3 * 2);
  unsigned short* n1_bf  = (unsigned short*)regA;
  unsigned short* qkv_bf = (unsigned short*)regA;
  unsigned short* proj_wt = (unsigned short*)alloc((size_t)Ec * Cc * 2);
  unsigned short* wqkv_t  = (unsigned short*)alloc((size_t)E3 * Ec * 2);
  unsigned short* wo_t    = (unsigned short*)alloc((size_t)Ec * Ec * 2);
  unsigned short* gp_bf   = (unsigned short*)alloc((size_t)Ec * Ec * 2);
  unsigned short* gat_t   = (unsigned short*)alloc((size_t)Ec * Ec * 2);
  unsigned short* m1_t    = (unsigned short*)alloc((size_t)Ec * Ec * 2);
  unsigned short* m2_t    = (unsigned short*)alloc((size_t)Ec * Ec * 2);
  unsigned short* gpgat_t = (unsigned short*)alloc((size_t)Ec * Ec * 2);
  float* bias2p = (float*)alloc((size_t)8 * Ec * 4);
  float* bias2  = (float*)alloc((size_t)Ec * 4);
  float* v_in   = (float*)alloc((size_t)Ntok * Ec * 4);
  unsigned short* v_in_bf = (unsigned short*)alloc((size_t)Ntok * Ec * 2);
  unsigned short* regE    = (unsigned short*)alloc((size_t)Ntok * Ec * 2);
  float* regF   = (float*)alloc((size_t)Ntok * Ec * 4);
  unsigned short* regG    = (unsigned short*)alloc((size_t)Ntok * Ec * 2);
  unsigned short* hN_bf   = (unsigned short*)alloc((size_t)Ntok * Ec * 2);
  float* regJ   = (float*)alloc((size_t)Ntok * Ec * 4);
  float* psum   = (float*)alloc((size_t)Ntok * 8 * 4);
  float* pss    = (float*)alloc((size_t)Ntok * 8 * 4);

  unsigned short* o_bf   = regE;
  unsigned short* h1_bf  = regE;
  float* x_attn = regF;
  float* n3_f   = regF;
  unsigned short* n2_bf  = regG;
  unsigned short* n3_bf  = regG;
  float* x_after = regJ;
  float* mlp_out = regJ;

  // 0) weights -> bf16
  WtArgs wa;
  wa.src[0] = proj_w; wa.dst[0] = proj_wt; wa.K[0] = Cc; wa.N[0] = Ec;  wa.mode[0] = 0;
  wa.src[1] = wqkv;   wa.dst[1] = wqkv_t;  wa.K[1] = Ec; wa.N[1] = E3;  wa.mode[1] = 0;
  wa.src[2] = wo;     wa.dst[2] = wo_t;    wa.K[2] = Ec; wa.N[2] = Ec;  wa.mode[2] = 0;
  wa.src[3] = gat_w;  wa.dst[3] = gat_t;   wa.K[3] = Ec; wa.N[3] = Ec;  wa.mode[3] = 0;
  wa.src[4] = mlp_w1; wa.dst[4] = m1_t;    wa.K[4] = Ec; wa.N[4] = Ec;  wa.mode[4] = 0;
  wa.src[5] = mlp_w2; wa.dst[5] = m2_t;    wa.K[5] = Ec; wa.N[5] = Ec;  wa.mode[5] = 0;
  wa.src[6] = gp_w;   wa.dst[6] = gp_bf;   wa.K[6] = Ec; wa.N[6] = Ec;  wa.mode[6] = 1;
  int cum = 0;
  for (int i = 0; i < 7; i++) { wa.off[i] = cum; cum += (wa.K[i] >> 5) * (wa.N[i] >> 5); }
  wa.off[7] = cum;
  k_wt<<<cum, 256, 0, stream>>>(wa);

  // 0b) fused gp@gat weight + bias2
  k_bias2p<<<dim3(3, 8), 256, 0, stream>>>(gat_w, gp_b, bias2p);
  k_bias2r<<<3, 256, 0, stream>>>(bias2p, bias2);
  gemm64_bf16<0, 2><<<dim3(Ec / 128, Ec / 64), 256, 0, stream>>>(
      gat_t, gp_bf, nullptr, nullptr, nullptr, gpgat_t, Ec, Ec, Ec);

  // 1) LN1 two-pass -> bf16 [M][C]
  k_ln1_stats<<<dim3(8, 64, 4), 256, 0, stream>>>(x, psum, pss);
  k_ln1_norm<<<dim3(16, 64, 4), 256, 0, stream>>>(x, ln1_g, ln1_b, psum, pss, n1_bf);
  // 2) v_in = n1 @ proj_w + proj_b  (f32 + bf16 out)
  gemm64_bf16<1, 3><<<dim3(Ec / 128, Ntok / 64), 256, 0, stream>>>(
      n1_bf, proj_wt, proj_b, nullptr, v_in, v_in_bf, Ntok, Ec, Cc);
  // 3) qkv = v_in @ wqkv + bqkv  (bf16 out)
  gemm_bf16<1, 2><<<dim3(E3 / 128, Ntok / 128), 512, 0, stream>>>(
      v_in_bf, wqkv_t, bqkv, nullptr, nullptr, qkv_bf, Ntok, E3, Ec);
  // 4) attention (XCD-grouped 1D grid)
  k_attn_mfma<<<16 * NHEAD * Bc, 256, 0, stream>>>(qkv_bf, o_bf);
  // 5) x_attn = v_in + o @ wo + bo  (f32)
  gemm64_bf16<2, 1><<<dim3(Ec / 128, Ntok / 64), 256, 0, stream>>>(
      o_bf, wo_t, bo, v_in, x_attn, nullptr, Ntok, Ec, Ec);
  // 6) n2 = LN(x_attn) -> bf16
  k_lnrow<0><<<Ntok, 256, 0, stream>>>(x_attn, ln2_g, ln2_b, nullptr, n2_bf);
  // 7+8 fused) hN = n2 @ (gp_w@gat_w) + gp_b@gat_w -> bf16
  gemm64_bf16<1, 2><<<dim3(Ec / 128, Ntok / 64), 256, 0, stream>>>(
      n2_bf, gpgat_t, bias2, nullptr, nullptr, hN_bf, Ntok, Ec, Ec);
  // 9+10 fused) GAT coefficients + aggregate + elu + residual -> x_after
  k_gatfull<<<Ntok, 256, 0, stream>>>(hN_bf, att_src, att_dst, x_attn, gat_b, x_after);
  // 11) n3 = LN(x_after) -> f32 + bf16
  k_lnrow<2><<<Ntok, 256, 0, stream>>>(x_after, ln3_g, ln3_b, n3_f, n3_bf);
  // 12) h1 = gelu(n3 @ mlp_w1 + mlp_b1) -> bf16
  gemm64_bf16<3, 2><<<dim3(Ec / 128, Ntok / 64), 256, 0, stream>>>(
      n3_bf, m1_t, mlp_b1, nullptr, nullptr, h1_bf, Ntok, Ec, Ec);
  // 13) mlp = h1 @ mlp_w2 + mlp_b2 -> f32
  gemm64_bf16<1, 1><<<dim3(Ec / 128, Ntok / 64), 256, 0, stream>>>(
      h1_bf, m2_t, mlp_b2, nullptr, mlp_out, nullptr, Ntok, Ec, Ec);
  // 14) out = LN(n3 + mlp), transposed to [B,E,H,W]
  k_lnout<<<256, 256, 0, stream>>>(n3_f, mlp_out, fn_g, fn_b, out);
}

// Round 11
// 248.559 us; speedup vs baseline: 1.1461x; 1.0215x over previous
//
#include <hip/hip_runtime.h>

// ---- problem constants ----
constexpr int Bc = 4;
constexpr int Cc = 2048;
constexpr int Sc = 1024;     // H*W = 32*32
constexpr int Ntok = 4096;   // B*S
constexpr int Ec = 768;
constexpr int E3 = 2304;
constexpr int NHEAD = 12;
constexpr int GHEAD = 4;
constexpr int DGAT = 192;

typedef __attribute__((ext_vector_type(8))) short short8_t;   // bf16x8 MFMA frag
typedef __attribute__((ext_vector_type(4))) short short4_t;
typedef __attribute__((ext_vector_type(8))) unsigned short u16x8;
typedef __attribute__((ext_vector_type(4))) float f32x4;

// software RNE f32->bf16
__device__ inline unsigned short f2bf(float f) {
  unsigned int u = __builtin_bit_cast(unsigned int, f);
  u += 0x7FFFu + ((u >> 16) & 1u);
  return (unsigned short)(u >> 16);
}
__device__ inline float bf2f(unsigned short h) {
  unsigned int u = ((unsigned int)h) << 16;
  return __builtin_bit_cast(float, u);
}
// packed hw cvt (P fragments only; verified absmax-neutral)
__device__ inline unsigned cvtpk(float lo, float hi) {
  unsigned r;
  asm("v_cvt_pk_bf16_f32 %0, %1, %2" : "=v"(r) : "v"(lo), "v"(hi));
  return r;
}

// ============ weight prep: 6 transposed + 1 identity bf16 cast ============
struct WtArgs {
  const float* src[7];
  unsigned short* dst[7];
  int K[7], N[7], mode[7];
  int off[8];
};
__global__ __launch_bounds__(256) void k_wt(WtArgs a) {
  __shared__ float t[32][33];
  int bid = blockIdx.x;
  int w = 0;
  while (w < 6 && bid >= a.off[w + 1]) ++w;
  int local = bid - a.off[w];
  int K = a.K[w], N = a.N[w];
  int ntn = N >> 5;
  int tk = local / ntn, tn = local - tk * ntn;
  int k0 = tk * 32, n0 = tn * 32;
  int tx = threadIdx.x & 31, ty = threadIdx.x >> 5;
  const float* src = a.src[w];
  unsigned short* dst = a.dst[w];
  if (a.mode[w]) {
#pragma unroll
    for (int i = 0; i < 4; i++)
      dst[(size_t)(k0 + ty + i * 8) * N + n0 + tx] =
          f2bf(src[(size_t)(k0 + ty + i * 8) * N + n0 + tx]);
    return;
  }
#pragma unroll
  for (int i = 0; i < 4; i++)
    t[ty + i * 8][tx] = src[(size_t)(k0 + ty + i * 8) * N + n0 + tx];
  __syncthreads();
#pragma unroll
  for (int i = 0; i < 4; i++)
    dst[(size_t)(n0 + ty + i * 8) * K + k0 + tx] = f2bf(t[tx][ty + i * 8]);
}

// ============ bias2 = gp_b @ gat_w: parallel partials (3x8 grid) + reduce ============
__global__ __launch_bounds__(256) void k_bias2p(const float* __restrict__ gat_w,
    const float* __restrict__ gp_b, float* __restrict__ part) {
  int m = blockIdx.x * 256 + threadIdx.x;
  int jc = blockIdx.y;
  float acc = 0.f;
#pragma unroll 8
  for (int j = jc * 96; j < jc * 96 + 96; j++)
    acc += gp_b[j] * gat_w[(size_t)j * Ec + m];
  part[jc * Ec + m] = acc;
}
__global__ __launch_bounds__(256) void k_bias2r(const float* __restrict__ part,
    float* __restrict__ bias2) {
  int m = blockIdx.x * 256 + threadIdx.x;
  float acc = 0.f;
#pragma unroll
  for (int j = 0; j < 8; j++) acc += part[j * Ec + m];
  bias2[m] = acc;
}

// ============ LN1 pass A ============
__global__ __launch_bounds__(256) void k_ln1_stats(const float* __restrict__ x,
    float* __restrict__ psum, float* __restrict__ pss) {
  int cc = blockIdx.x, st = blockIdx.y, b = blockIdx.z;
  int sl = threadIdx.x & 15, cl = threadIdx.x >> 4;
  int s = st * 16 + sl;
  const float* xb = x + (size_t)b * Cc * Sc + s;
  float sum = 0.f, ss = 0.f;
#pragma unroll
  for (int t = 0; t < 16; t++) {
    int c = cc * 256 + cl + t * 16;
    float v = xb[(size_t)c * Sc];
    sum += v; ss += v * v;
  }
  __shared__ float rs0[16][17], rs1[16][17];
  rs0[cl][sl] = sum; rs1[cl][sl] = ss;
  __syncthreads();
  if (cl == 0) {
    float a = 0.f, q = 0.f;
#pragma unroll
    for (int i = 0; i < 16; i++) { a += rs0[i][sl]; q += rs1[i][sl]; }
    size_t bs = (size_t)(b * Sc + st * 16 + sl);
    psum[bs * 8 + cc] = a;
    pss[bs * 8 + cc] = q;
  }
}

// ============ LN1 pass B ============
__global__ __launch_bounds__(256) void k_ln1_norm(const float* __restrict__ x,
    const float* __restrict__ g, const float* __restrict__ bt,
    const float* __restrict__ psum, const float* __restrict__ pss,
    unsigned short* __restrict__ out) {
  int cc = blockIdx.x, st = blockIdx.y, b = blockIdx.z;
  int sl = threadIdx.x & 15, cl = threadIdx.x >> 4;
  int s = st * 16 + sl;
  __shared__ float red[16][17];
  __shared__ float mean_s[16], rstd_s[16];
  int t8 = cl;
  size_t bsrow = (size_t)(b * Sc + st * 16 + sl);
  float v = (t8 < 8) ? psum[bsrow * 8 + t8] : pss[bsrow * 8 + (t8 - 8)];
  red[t8][sl] = v;
  __syncthreads();
  if (threadIdx.x < 16) {
    float s0 = 0.f, s1 = 0.f;
#pragma unroll
    for (int i = 0; i < 8; i++) { s0 += red[i][threadIdx.x]; s1 += red[i + 8][threadIdx.x]; }
    float mean = s0 / Cc;
    mean_s[threadIdx.x] = mean;
    rstd_s[threadIdx.x] = rsqrtf(s1 / Cc - mean * mean + 1e-5f);
  }
  __syncthreads();
  float mean = mean_s[sl], rstd = rstd_s[sl];
  const float* xb = x + (size_t)b * Cc * Sc + s;
  __shared__ unsigned short Tc[16][136];
  int cb = cc * 128;
#pragma unroll
  for (int t = 0; t < 8; t++) {
    int c = cb + cl + t * 16;
    float xv = xb[(size_t)c * Sc];
    Tc[sl][cl + t * 16] = f2bf((xv - mean) * rstd * g[c] + bt[c]);
  }
  __syncthreads();
  int rl = threadIdx.x >> 4, el = threadIdx.x & 15;
  unsigned short* ob = out + ((size_t)(b * Sc) + st * 16 + rl) * Cc + cb;
  *(u16x8*)&ob[el * 8] = *(const u16x8*)&Tc[rl][el * 8];
}

// ============ bf16 MFMA GEMM, 128x128 tile, 512 thr, reg-dbuf (for qkv) ============
template<int EPI, int OUTM>
__global__ __launch_bounds__(512) void gemm_bf16(
    const unsigned short* __restrict__ A, const unsigned short* __restrict__ Bt,
    const float* __restrict__ bias, const float* __restrict__ res,
    float* __restrict__ Cf, unsigned short* __restrict__ Cb,
    int M, int N, int K) {
  __shared__ unsigned short As[128][72];
  __shared__ unsigned short Bs[128][72];
  int tid = threadIdx.x;
  int w = tid >> 6, lane = tid & 63, g = lane >> 4, l16 = lane & 15;
  int wm = w >> 2, wn = w & 3;
  int m0 = blockIdx.y * 128, n0 = blockIdx.x * 128;
  int r0 = tid >> 3, ch0 = (tid & 7) * 8;
  int r1 = r0 + 64;
  const unsigned short* Arow0 = A + (size_t)(m0 + r0) * K + ch0;
  const unsigned short* Arow1 = A + (size_t)(m0 + r1) * K + ch0;
  const unsigned short* Brow0 = Bt + (size_t)(n0 + r0) * K + ch0;
  const unsigned short* Brow1 = Bt + (size_t)(n0 + r1) * K + ch0;
  u16x8 ra0 = *(const u16x8*)Arow0;
  u16x8 ra1 = *(const u16x8*)Arow1;
  u16x8 rb0 = *(const u16x8*)Brow0;
  u16x8 rb1 = *(const u16x8*)Brow1;
  f32x4 acc[4][2] = {};
  for (int k0 = 0; k0 < K; k0 += 64) {
    __syncthreads();
    *(u16x8*)&As[r0][ch0] = ra0;
    *(u16x8*)&As[r1][ch0] = ra1;
    *(u16x8*)&Bs[r0][ch0] = rb0;
    *(u16x8*)&Bs[r1][ch0] = rb1;
    __syncthreads();
    if (k0 + 64 < K) {
      ra0 = *(const u16x8*)(Arow0 + k0 + 64);
      ra1 = *(const u16x8*)(Arow1 + k0 + 64);
      rb0 = *(const u16x8*)(Brow0 + k0 + 64);
      rb1 = *(const u16x8*)(Brow1 + k0 + 64);
    }
#pragma unroll
    for (int ks = 0; ks < 2; ks++) {
      short8_t af[4], bf[2];
#pragma unroll
      for (int i = 0; i < 4; i++)
        af[i] = *(const short8_t*)&As[wm * 64 + i * 16 + l16][ks * 32 + g * 8];
#pragma unroll
      for (int j = 0; j < 2; j++)
        bf[j] = *(const short8_t*)&Bs[wn * 32 + j * 16 + l16][ks * 32 + g * 8];
#pragma unroll
      for (int mi = 0; mi < 4; mi++)
#pragma unroll
        for (int ni = 0; ni < 2; ni++)
          acc[mi][ni] = __builtin_amdgcn_mfma_f32_16x16x32_bf16(af[mi], bf[ni], acc[mi][ni], 0, 0, 0);
    }
  }
#pragma unroll
  for (int mi = 0; mi < 4; mi++) {
#pragma unroll
    for (int ni = 0; ni < 2; ni++) {
      int n = n0 + wn * 32 + ni * 16 + l16;
      float bv = 0.f;
      if (EPI != 0) bv = bias[n];
#pragma unroll
      for (int r = 0; r < 4; r++) {
        int m = m0 + wm * 64 + mi * 16 + g * 4 + r;
        float c = acc[mi][ni][r] + bv;
        if (EPI == 2) c += res[(size_t)m * N + n];
        if (EPI == 3) c = 0.5f * c * (1.f + erff(c * 0.70710678118f));
        if (OUTM & 1) Cf[(size_t)m * N + n] = c;
        if (OUTM & 2) Cb[(size_t)m * N + n] = f2bf(c);
      }
    }
  }
}

// ============ bf16 MFMA GEMM, 64x128 tile, 256 thr = 4 waves (2Mx2N), reg-dbuf ============
template<int EPI, int OUTM>
__global__ __launch_bounds__(256) void gemm64_bf16(
    const unsigned short* __restrict__ A, const unsigned short* __restrict__ Bt,
    const float* __restrict__ bias, const float* __restrict__ res,
    float* __restrict__ Cf, unsigned short* __restrict__ Cb,
    int M, int N, int K) {
  __shared__ unsigned short As[64][72];
  __shared__ unsigned short Bs[128][72];
  int tid = threadIdx.x;
  int w = tid >> 6, lane = tid & 63, g = lane >> 4, l16 = lane & 15;
  int wm = w >> 1, wn = w & 1;           // wave tile 32M x 64N
  int m0 = blockIdx.y * 64, n0 = blockIdx.x * 128;
  int r0 = tid >> 3, ch0 = (tid & 7) * 8;
  const unsigned short* ArowA = A + (size_t)(m0 + r0) * K + ch0;
  const unsigned short* ArowB = A + (size_t)(m0 + r0 + 32) * K + ch0;
  const unsigned short* Brow0 = Bt + (size_t)(n0 + r0) * K + ch0;
  const unsigned short* Brow1 = Bt + (size_t)(n0 + r0 + 32) * K + ch0;
  const unsigned short* Brow2 = Bt + (size_t)(n0 + r0 + 64) * K + ch0;
  const unsigned short* Brow3 = Bt + (size_t)(n0 + r0 + 96) * K + ch0;
  u16x8 raA = *(const u16x8*)ArowA;
  u16x8 raB = *(const u16x8*)ArowB;
  u16x8 rb0 = *(const u16x8*)Brow0;
  u16x8 rb1 = *(const u16x8*)Brow1;
  u16x8 rb2 = *(const u16x8*)Brow2;
  u16x8 rb3 = *(const u16x8*)Brow3;
  f32x4 acc[2][4] = {};
  for (int k0 = 0; k0 < K; k0 += 64) {
    __syncthreads();
    *(u16x8*)&As[r0][ch0] = raA;
    *(u16x8*)&As[r0 + 32][ch0] = raB;
    *(u16x8*)&Bs[r0][ch0] = rb0;
    *(u16x8*)&Bs[r0 + 32][ch0] = rb1;
    *(u16x8*)&Bs[r0 + 64][ch0] = rb2;
    *(u16x8*)&Bs[r0 + 96][ch0] = rb3;
    __syncthreads();
    if (k0 + 64 < K) {
      raA = *(const u16x8*)(ArowA + k0 + 64);
      raB = *(const u16x8*)(ArowB + k0 + 64);
      rb0 = *(const u16x8*)(Brow0 + k0 + 64);
      rb1 = *(const u16x8*)(Brow1 + k0 + 64);
      rb2 = *(const u16x8*)(Brow2 + k0 + 64);
      rb3 = *(const u16x8*)(Brow3 + k0 + 64);
    }
#pragma unroll
    for (int ks = 0; ks < 2; ks++) {
      short8_t af[2], bf[4];
#pragma unroll
      for (int i = 0; i < 2; i++)
        af[i] = *(const short8_t*)&As[wm * 32 + i * 16 + l16][ks * 32 + g * 8];
#pragma unroll
      for (int j = 0; j < 4; j++)
        bf[j] = *(const short8_t*)&Bs[wn * 64 + j * 16 + l16][ks * 32 + g * 8];
#pragma unroll
      for (int mi = 0; mi < 2; mi++)
#pragma unroll
        for (int ni = 0; ni < 4; ni++)
          acc[mi][ni] = __builtin_amdgcn_mfma_f32_16x16x32_bf16(af[mi], bf[ni], acc[mi][ni], 0, 0, 0);
    }
  }
#pragma unroll
  for (int mi = 0; mi < 2; mi++) {
#pragma unroll
    for (int ni = 0; ni < 4; ni++) {
      int n = n0 + wn * 64 + ni * 16 + l16;
      float bv = 0.f;
      if (EPI != 0) bv = bias[n];
#pragma unroll
      for (int r = 0; r < 4; r++) {
        int m = m0 + wm * 32 + mi * 16 + g * 4 + r;
        float c = acc[mi][ni][r] + bv;
        if (EPI == 2) c += res[(size_t)m * N + n];
        if (EPI == 3) c = 0.5f * c * (1.f + erff(c * 0.70710678118f));
        if (OUTM & 1) Cf[(size_t)m * N + n] = c;
        if (OUTM & 2) Cb[(size_t)m * N + n] = f2bf(c);
      }
    }
  }
}

// ============ MHSA: swapped-QK MFMA flash, XCD-grouped grid, defer-max, cvt_pk P ============
__global__ __launch_bounds__(256) void k_attn_mfma(const unsigned short* __restrict__ qkv,
    unsigned short* __restrict__ o) {
  __shared__ unsigned short Ks[64][72];
  __shared__ unsigned short Vs[4608];
  __shared__ unsigned short Plb[4][16][72];
  int fid = blockIdx.x;
  int xcd = fid & 7, t = fid >> 3;
  int qt = t & 15;
  int hb = (t >> 4) * 8 + xcd;
  int h = hb % NHEAD, b = hb / NHEAD;
  int tid = threadIdx.x;
  int w = tid >> 6, lane = tid & 63;
  int g = lane >> 4, l16 = lane & 15;
  const unsigned short* base  = qkv + (size_t)b * Sc * E3;
  const unsigned short* kbase = base + Ec + h * 64;
  const unsigned short* vbase = base + 2 * Ec + h * 64;
  int q0 = qt * 64 + w * 16;

  short8_t qf[2];
#pragma unroll
  for (int ks = 0; ks < 2; ks++) {
    short8_t f = *(const short8_t*)&base[(size_t)(q0 + l16) * E3 + h * 64 + ks * 32 + g * 8];
#pragma unroll
    for (int e = 0; e < 8; e++)
      f[e] = (short)f2bf(bf2f((unsigned short)f[e]) * 0.125f);
    qf[ks] = f;
  }

  int r0s = tid >> 3, ch0s = (tid & 7) * 8;
  int r1s = r0s + 32;
  int voff0 = (r0s >> 2) * 288 + (ch0s >> 4) * 72 + (r0s & 3) * 16 + ((ch0s >> 3) & 1) * 8;
  int voff1 = (r1s >> 2) * 288 + (ch0s >> 4) * 72 + (r1s & 3) * 16 + ((ch0s >> 3) & 1) * 8;
  const unsigned short* krow0 = kbase + (size_t)r0s * E3 + ch0s;
  const unsigned short* krow1 = kbase + (size_t)r1s * E3 + ch0s;
  const unsigned short* vrow0 = vbase + (size_t)r0s * E3 + ch0s;
  const unsigned short* vrow1 = vbase + (size_t)r1s * E3 + ch0s;
  constexpr size_t KTS = (size_t)64 * E3;

  u16x8 rk0 = *(const u16x8*)krow0;
  u16x8 rk1 = *(const u16x8*)krow1;
  u16x8 rv0 = *(const u16x8*)vrow0;
  u16x8 rv1 = *(const u16x8*)vrow1;

  f32x4 o_acc[4] = {};
  float m_r = -1e30f, l_r = 0.f;

  for (int kt = 0; kt < 16; kt++) {
    __syncthreads();
    *(u16x8*)&Ks[r0s][ch0s] = rk0;
    *(u16x8*)&Ks[r1s][ch0s] = rk1;
    *(u16x8*)&Vs[voff0] = rv0;
    *(u16x8*)&Vs[voff1] = rv1;
    __syncthreads();
    if (kt < 15) {
      size_t off = (size_t)(kt + 1) * KTS;
      rk0 = *(const u16x8*)(krow0 + off);
      rk1 = *(const u16x8*)(krow1 + off);
      rv0 = *(const u16x8*)(vrow0 + off);
      rv1 = *(const u16x8*)(vrow1 + off);
    }

    f32x4 s_acc[4] = {};
#pragma unroll
    for (int nt = 0; nt < 4; nt++) {
#pragma unroll
      for (int ks = 0; ks < 2; ks++) {
        short8_t kf = *(const short8_t*)&Ks[nt * 16 + l16][ks * 32 + g * 8];
        s_acc[nt] = __builtin_amdgcn_mfma_f32_16x16x32_bf16(kf, qf[ks], s_acc[nt], 0, 0, 0);
      }
    }

    float mx = s_acc[0][0];
#pragma unroll
    for (int nt = 0; nt < 4; nt++)
#pragma unroll
      for (int r = 0; r < 4; r++) mx = fmaxf(mx, s_acc[nt][r]);
    mx = fmaxf(mx, __shfl_xor(mx, 16));
    mx = fmaxf(mx, __shfl_xor(mx, 32));

    if (!__all(mx - m_r <= 8.f)) {
      float mn = fmaxf(m_r, mx);
      float sc = __expf(m_r - mn);
      m_r = mn;
      l_r *= sc;
      float osc[4];
#pragma unroll
      for (int r = 0; r < 4; r++) osc[r] = __shfl(sc, g * 4 + r);
#pragma unroll
      for (int dt = 0; dt < 4; dt++)
#pragma unroll
        for (int r = 0; r < 4; r++) o_acc[dt][r] *= osc[r];
    }

    float ts = 0.f;
#pragma unroll
    for (int nt = 0; nt < 4; nt++)
#pragma unroll
      for (int r = 0; r < 4; r++) {
        float pv = __expf(s_acc[nt][r] - m_r);
        s_acc[nt][r] = pv;
        ts += pv;
      }
    ts += __shfl_xor(ts, 16);
    ts += __shfl_xor(ts, 32);
    l_r += ts;

#pragma unroll
    for (int nt = 0; nt < 4; nt++) {
      *(unsigned*)&Plb[w][l16][nt * 16 + g * 4] = cvtpk(s_acc[nt][0], s_acc[nt][1]);
      *(unsigned*)&Plb[w][l16][nt * 16 + g * 4 + 2] = cvtpk(s_acc[nt][2], s_acc[nt][3]);
    }

#pragma unroll
    for (int ks = 0; ks < 2; ks++) {
      short8_t pf = *(const short8_t*)&Plb[w][l16][ks * 32 + g * 8];
      short4_t lo0, lo1, lo2, lo3, hi0, hi1, hi2, hi3;
      unsigned a0 = (unsigned)(uintptr_t)&Vs[(ks * 8 + g * 2) * 288 + 0 * 72 + l16] * 1u;
      unsigned a1 = a0 + 144, a2 = a0 + 288, a3 = a0 + 432;
      asm volatile("ds_read_b64_tr_b16 %0, %1" : "=v"(lo0) : "v"(a0));
      asm volatile("ds_read_b64_tr_b16 %0, %1 offset:576" : "=v"(hi0) : "v"(a0));
      asm volatile("ds_read_b64_tr_b16 %0, %1" : "=v"(lo1) : "v"(a1));
      asm volatile("ds_read_b64_tr_b16 %0, %1 offset:576" : "=v"(hi1) : "v"(a1));
      asm volatile("ds_read_b64_tr_b16 %0, %1" : "=v"(lo2) : "v"(a2));
      asm volatile("ds_read_b64_tr_b16 %0, %1 offset:576" : "=v"(hi2) : "v"(a2));
      asm volatile("ds_read_b64_tr_b16 %0, %1" : "=v"(lo3) : "v"(a3));
      asm volatile("ds_read_b64_tr_b16 %0, %1 offset:576" : "=v"(hi3) : "v"(a3));
      asm volatile("s_waitcnt lgkmcnt(0)");
      __builtin_amdgcn_sched_barrier(0);
      short4_t lo[4] = {lo0, lo1, lo2, lo3};
      short4_t hi[4] = {hi0, hi1, hi2, hi3};
#pragma unroll
      for (int dt = 0; dt < 4; dt++) {
        short8_t vf;
#pragma unroll
        for (int e = 0; e < 4; e++) { vf[e] = lo[dt][e]; vf[4 + e] = hi[dt][e]; }
        o_acc[dt] = __builtin_amdgcn_mfma_f32_16x16x32_bf16(pf, vf, o_acc[dt], 0, 0, 0);
      }
    }
  }

  float linv = 1.f / l_r;
  float inv4[4];
#pragma unroll
  for (int r = 0; r < 4; r++) inv4[r] = __shfl(linv, g * 4 + r);
  unsigned short* obase = o + (size_t)(b * Sc + q0) * Ec + h * 64;
#pragma unroll
  for (int r = 0; r < 4; r++) {
    int qrow = g * 4 + r;
#pragma unroll
    for (int dt = 0; dt < 4; dt++)
      obase[(size_t)qrow * Ec + dt * 16 + l16] = f2bf(o_acc[dt][r] * inv4[r]);
  }
}

// ============ LN over rows of E=768 (MODE 0: bf16 out) ============
template<int MODE>
__global__ __launch_bounds__(256) void k_lnrow(const float* __restrict__ in,
    const float* __restrict__ g, const float* __restrict__ bt,
    float* __restrict__ outf, unsigned short* __restrict__ outb) {
  int row = blockIdx.x;
  int tid = threadIdx.x;
  __shared__ float buf[Ec];
  __shared__ float rsum[4], rss[4];
  float sum = 0.f, ss = 0.f;
  for (int i = tid; i < Ec; i += 256) {
    float v = in[(size_t)row * Ec + i];
    buf[i] = v; sum += v; ss += v * v;
  }
#pragma unroll
  for (int off = 32; off > 0; off >>= 1) {
    sum += __shfl_xor(sum, off); ss += __shfl_xor(ss, off);
  }
  if ((tid & 63) == 0) { rsum[tid >> 6] = sum; rss[tid >> 6] = ss; }
  __syncthreads();
  sum = rsum[0] + rsum[1] + rsum[2] + rsum[3];
  ss = rss[0] + rss[1] + rss[2] + rss[3];
  float mean = sum / Ec;
  float rstd = rsqrtf(ss / Ec - mean * mean + 1e-5f);
  for (int i = tid; i < Ec; i += 256) {
    float v = (buf[i] - mean) * rstd * g[i] + bt[i];
    if (MODE == 2) outf[(size_t)row * Ec + i] = v;
    outb[(size_t)row * Ec + i] = f2bf(v);
  }
}

// ============ final LN ============
__global__ __launch_bounds__(256) void k_lnout(const float* __restrict__ in,
    const float* __restrict__ res, const float* __restrict__ g,
    const float* __restrict__ bt, float* __restrict__ out) {
  int r0 = blockIdx.x * 16;
  int b = r0 >> 10, s0 = r0 & 1023;
  __shared__ float Tr[16][772];
  __shared__ float mean_s[16], rstd_s[16];
  int rl = threadIdx.x >> 4, el = threadIdx.x & 15;
  const float* ip = in + (size_t)(r0 + rl) * Ec;
  const float* rp = res + (size_t)(r0 + rl) * Ec;
  float sum = 0.f, ss = 0.f;
  for (int i = el; i < Ec; i += 16) {
    float v = ip[i] + rp[i];
    Tr[rl][i] = v; sum += v; ss += v * v;
  }
#pragma unroll
  for (int off = 8; off; off >>= 1) {
    sum += __shfl_xor(sum, off); ss += __shfl_xor(ss, off);
  }
  if (el == 0) {
    float mean = sum / Ec;
    mean_s[rl] = mean;
    rstd_s[rl] = rsqrtf(ss / Ec - mean * mean + 1e-5f);
  }
  __syncthreads();
  int sl = threadIdx.x & 15, il = threadIdx.x >> 4;
  float mean = mean_s[sl], rstd = rstd_s[sl];
  for (int i = il; i < Ec; i += 16)
    out[((size_t)b * Ec + i) * Sc + s0 + sl] = (Tr[sl][i] - mean) * rstd * g[i] + bt[i];
}

// ============ fused GAT + LN3: stage 9 nbr rows, coeffs, aggregate, then LN in-place ============
// Produces n3_f (f32) + n3_bf (bf16); x_after is never materialized.
__global__ __launch_bounds__(256) void k_gatfull(const unsigned short* __restrict__ hNb,
    const float* __restrict__ att_src, const float* __restrict__ att_dst,
    const float* __restrict__ x_attn, const float* __restrict__ gat_b,
    const float* __restrict__ ln3_g, const float* __restrict__ ln3_b,
    float* __restrict__ n3_f, unsigned short* __restrict__ n3_bf) {
  int n = blockIdx.x;
  int b = n >> 10, s = n & 1023, r = s >> 5, c = s & 31;
  __shared__ int nbr[9];
  __shared__ unsigned short hrows[9][Ec];   // 13.8KB
  __shared__ float alpha[GHEAD][9];
  __shared__ float xrow[Ec];                // x_after row (LN input)
  __shared__ float rsum[4], rss[4];
  int tid = threadIdx.x;
  if (tid < 9) {
    int dr = tid / 3 - 1, dc = tid % 3 - 1;
    int rr = r + dr, cc = c + dc;
    int ok = (rr >= 0 && rr < 32 && cc >= 0 && cc < 32);
    if (dr == -1 && dc == 1 && cc == 31) ok = 0;
    if (dr == 1 && dc == -1 && c == 31) ok = 0;
    nbr[tid] = ok ? ((b << 10) + (rr << 5) + cc) : -1;
  }
  __syncthreads();
  // stage valid neighbor rows
  for (int i = tid; i < 9 * 96; i += 256) {
    int j = i / 96, e8 = i - j * 96;
    if (nbr[j] >= 0)
      *(u16x8*)&hrows[j][e8 * 8] = *(const u16x8*)&hNb[(size_t)nbr[j] * Ec + e8 * 8];
  }
  __syncthreads();
  // per-wave head: a_s dots + a_d(self)
  int w = tid >> 6, lane = tid & 63;
  {
    float pd = 0.f;
#pragma unroll
    for (int t = 0; t < 3; t++) {
      int d = w * DGAT + lane + t * 64;
      pd += bf2f(hrows[4][d]) * att_dst[d];
    }
#pragma unroll
    for (int off = 32; off; off >>= 1) pd += __shfl_xor(pd, off);
    float as_j[9];
#pragma unroll
    for (int j = 0; j < 9; j++) {
      float p = 0.f;
      if (nbr[j] >= 0) {
#pragma unroll
        for (int t = 0; t < 3; t++) {
          int d = w * DGAT + lane + t * 64;
          p += bf2f(hrows[j][d]) * att_src[d];
        }
      }
#pragma unroll
      for (int off = 32; off; off >>= 1) p += __shfl_xor(p, off);
      as_j[j] = p;
    }
    if (lane == 0) {
      float ev[9]; float m = -1e30f;
#pragma unroll
      for (int j = 0; j < 9; j++) {
        if (nbr[j] >= 0) {
          float e = as_j[j] + pd;
          e = e > 0.f ? e : 0.2f * e;
          ev[j] = e; m = fmaxf(m, e);
        } else ev[j] = -1e30f;
      }
      float den = 0.f;
#pragma unroll
      for (int j = 0; j < 9; j++) {
        float xv = (nbr[j] >= 0) ? expf(ev[j] - m) : 0.f;
        ev[j] = xv; den += xv;
      }
      float inv = 1.f / den;
#pragma unroll
      for (int j = 0; j < 9; j++) alpha[w][j] = ev[j] * inv;
    }
  }
  __syncthreads();
  // aggregate + elu + residual -> xrow; LN stats (same order as k_lnrow)
  float sum = 0.f, ss = 0.f;
  for (int e = tid; e < Ec; e += 256) {
    int h = e / DGAT;
    float acc = 0.f;
#pragma unroll
    for (int j = 0; j < 9; j++) {
      if (nbr[j] >= 0) acc += alpha[h][j] * bf2f(hrows[j][e]);
    }
    float v = acc + gat_b[e];
    v = v > 0.f ? v : expf(v) - 1.f;
    v += x_attn[(size_t)n * Ec + e];
    xrow[e] = v;
    sum += v; ss += v * v;
  }
#pragma unroll
  for (int off = 32; off > 0; off >>= 1) {
    sum += __shfl_xor(sum, off); ss += __shfl_xor(ss, off);
  }
  if ((tid & 63) == 0) { rsum[tid >> 6] = sum; rss[tid >> 6] = ss; }
  __syncthreads();
  sum = rsum[0] + rsum[1] + rsum[2] + rsum[3];
  ss = rss[0] + rss[1] + rss[2] + rss[3];
  float mean = sum / Ec;
  float rstd = rsqrtf(ss / Ec - mean * mean + 1e-5f);
  for (int e = tid; e < Ec; e += 256) {
    float v = (xrow[e] - mean) * rstd * ln3_g[e] + ln3_b[e];
    n3_f[(size_t)n * Ec + e] = v;
    n3_bf[(size_t)n * Ec + e] = f2bf(v);
  }
}

extern "C" void kernel_launch(void* const* d_in, const int* in_sizes, int n_in,
                              void* d_out, int out_size, void* d_ws, size_t ws_size,
                              hipStream_t stream) {
  (void)in_sizes; (void)n_in; (void)out_size; (void)ws_size;
  const float* x      = (const float*)d_in[0];
  const float* ln1_g  = (const float*)d_in[1];
  const float* ln1_b  = (const float*)d_in[2];
  const float* proj_w = (const float*)d_in[3];
  const float* proj_b = (const float*)d_in[4];
  const float* wqkv   = (const float*)d_in[5];
  const float* bqkv   = (const float*)d_in[6];
  const float* wo     = (const float*)d_in[7];
  const float* bo     = (const float*)d_in[8];
  const float* ln2_g  = (const float*)d_in[9];
  const float* ln2_b  = (const float*)d_in[10];
  const float* gp_w   = (const float*)d_in[11];
  const float* gp_b   = (const float*)d_in[12];
  const float* gat_w  = (const float*)d_in[13];
  const float* att_src= (const float*)d_in[14];
  const float* att_dst= (const float*)d_in[15];
  const float* gat_b  = (const float*)d_in[16];
  const float* ln3_g  = (const float*)d_in[17];
  const float* ln3_b  = (const float*)d_in[18];
  const float* mlp_w1 = (const float*)d_in[19];
  const float* mlp_b1 = (const float*)d_in[20];
  const float* mlp_w2 = (const float*)d_in[21];
  const float* mlp_b2 = (const float*)d_in[22];
  const float* fn_g   = (const float*)d_in[23];
  const float* fn_b   = (const float*)d_in[24];
  float* out = (float*)d_out;

  // ---- workspace layout ----
  char* p = (char*)d_ws;
  auto alloc = [&](size_t bytes) { char* q = p; p += (bytes + 255) & ~(size_t)255; return q; };
  char* regA      = alloc((size_t)Ntok * E3 * 2);
  unsigned short* n1_bf  = (unsigned short*)regA;
  unsigned short* qkv_bf = (unsigned short*)regA;
  unsigned short* proj_wt = (unsigned short*)alloc((size_t)Ec * Cc * 2);
  unsigned short* wqkv_t  = (unsigned short*)alloc((size_t)E3 * Ec * 2);
  unsigned short* wo_t    = (unsigned short*)alloc((size_t)Ec * Ec * 2);
  unsigned short* gp_bf   = (unsigned short*)alloc((size_t)Ec * Ec * 2);
  unsigned short* gat_t   = (unsigned short*)alloc((size_t)Ec * Ec * 2);
  unsigned short* m1_t    = (unsigned short*)alloc((size_t)Ec * Ec * 2);
  unsigned short* m2_t    = (unsigned short*)alloc((size_t)Ec * Ec * 2);
  unsigned short* gpgat_t = (unsigned short*)alloc((size_t)Ec * Ec * 2);
  float* bias2p = (float*)alloc((size_t)8 * Ec * 4);
  float* bias2  = (float*)alloc((size_t)Ec * 4);
  float* v_in   = (float*)alloc((size_t)Ntok * Ec * 4);
  unsigned short* v_in_bf = (unsigned short*)alloc((size_t)Ntok * Ec * 2);
  unsigned short* regE    = (unsigned short*)alloc((size_t)Ntok * Ec * 2);
  float* regF   = (float*)alloc((size_t)Ntok * Ec * 4);   // x_attn
  unsigned short* regG    = (unsigned short*)alloc((size_t)Ntok * Ec * 2); // n2_bf -> n3_bf
  unsigned short* hN_bf   = (unsigned short*)alloc((size_t)Ntok * Ec * 2);
  float* regJ   = (float*)alloc((size_t)Ntok * Ec * 4);   // n3_f
  float* regK   = (float*)alloc((size_t)Ntok * Ec * 4);   // mlp_out
  float* psum   = (float*)alloc((size_t)Ntok * 8 * 4);
  float* pss    = (float*)alloc((size_t)Ntok * 8 * 4);

  unsigned short* o_bf   = regE;
  unsigned short* h1_bf  = regE;
  float* x_attn = regF;
  unsigned short* n2_bf  = regG;
  unsigned short* n3_bf  = regG;
  float* n3_f   = regJ;
  float* mlp_out = regK;

  // 0) weights -> bf16
  WtArgs wa;
  wa.src[0] = proj_w; wa.dst[0] = proj_wt; wa.K[0] = Cc; wa.N[0] = Ec;  wa.mode[0] = 0;
  wa.src[1] = wqkv;   wa.dst[1] = wqkv_t;  wa.K[1] = Ec; wa.N[1] = E3;  wa.mode[1] = 0;
  wa.src[2] = wo;     wa.dst[2] = wo_t;    wa.K[2] = Ec; wa.N[2] = Ec;  wa.mode[2] = 0;
  wa.src[3] = gat_w;  wa.dst[3] = gat_t;   wa.K[3] = Ec; wa.N[3] = Ec;  wa.mode[3] = 0;
  wa.src[4] = mlp_w1; wa.dst[4] = m1_t;    wa.K[4] = Ec; wa.N[4] = Ec;  wa.mode[4] = 0;
  wa.src[5] = mlp_w2; wa.dst[5] = m2_t;    wa.K[5] = Ec; wa.N[5] = Ec;  wa.mode[5] = 0;
  wa.src[6] = gp_w;   wa.dst[6] = gp_bf;   wa.K[6] = Ec; wa.N[6] = Ec;  wa.mode[6] = 1;
  int cum = 0;
  for (int i = 0; i < 7; i++) { wa.off[i] = cum; cum += (wa.K[i] >> 5) * (wa.N[i] >> 5); }
  wa.off[7] = cum;
  k_wt<<<cum, 256, 0, stream>>>(wa);

  // 0b) fused gp@gat weight + bias2
  k_bias2p<<<dim3(3, 8), 256, 0, stream>>>(gat_w, gp_b, bias2p);
  k_bias2r<<<3, 256, 0, stream>>>(bias2p, bias2);
  gemm64_bf16<0, 2><<<dim3(Ec / 128, Ec / 64), 256, 0, stream>>>(
      gat_t, gp_bf, nullptr, nullptr, nullptr, gpgat_t, Ec, Ec, Ec);

  // 1) LN1 two-pass -> bf16 [M][C]
  k_ln1_stats<<<dim3(8, 64, 4), 256, 0, stream>>>(x, psum, pss);
  k_ln1_norm<<<dim3(16, 64, 4), 256, 0, stream>>>(x, ln1_g, ln1_b, psum, pss, n1_bf);
  // 2) v_in = n1 @ proj_w + proj_b  (f32 + bf16 out)
  gemm64_bf16<1, 3><<<dim3(Ec / 128, Ntok / 64), 256, 0, stream>>>(
      n1_bf, proj_wt, proj_b, nullptr, v_in, v_in_bf, Ntok, Ec, Cc);
  // 3) qkv = v_in @ wqkv + bqkv  (bf16 out)
  gemm_bf16<1, 2><<<dim3(E3 / 128, Ntok / 128), 512, 0, stream>>>(
      v_in_bf, wqkv_t, bqkv, nullptr, nullptr, qkv_bf, Ntok, E3, Ec);
  // 4) attention (XCD-grouped 1D grid)
  k_attn_mfma<<<16 * NHEAD * Bc, 256, 0, stream>>>(qkv_bf, o_bf);
  // 5) x_attn = v_in + o @ wo + bo  (f32)
  gemm64_bf16<2, 1><<<dim3(Ec / 128, Ntok / 64), 256, 0, stream>>>(
      o_bf, wo_t, bo, v_in, x_attn, nullptr, Ntok, Ec, Ec);
  // 6) n2 = LN(x_attn) -> bf16
  k_lnrow<0><<<Ntok, 256, 0, stream>>>(x_attn, ln2_g, ln2_b, nullptr, n2_bf);
  // 7+8 fused) hN = n2 @ (gp_w@gat_w) + gp_b@gat_w -> bf16
  gemm64_bf16<1, 2><<<dim3(Ec / 128, Ntok / 64), 256, 0, stream>>>(
      n2_bf, gpgat_t, bias2, nullptr, nullptr, hN_bf, Ntok, Ec, Ec);
  // 9+10+11 fused) GAT coeffs + aggregate + elu + residual + LN3 -> n3_f, n3_bf
  k_gatfull<<<Ntok, 256, 0, stream>>>(hN_bf, att_src, att_dst, x_attn, gat_b,
                                      ln3_g, ln3_b, n3_f, n3_bf);
  // 12) h1 = gelu(n3 @ mlp_w1 + mlp_b1) -> bf16
  gemm64_bf16<3, 2><<<dim3(Ec / 128, Ntok / 64), 256, 0, stream>>>(
      n3_bf, m1_t, mlp_b1, nullptr, nullptr, h1_bf, Ntok, Ec, Ec);
  // 13) mlp = h1 @ mlp_w2 + mlp_b2 -> f32
  gemm64_bf16<1, 1><<<dim3(Ec / 128, Ntok / 64), 256, 0, stream>>>(
      h1_bf, m2_t, mlp_b2, nullptr, mlp_out, nullptr, Ntok, Ec, Ec);
  // 14) out = LN(n3 + mlp), transposed to [B,E,H,W]
  k_lnout<<<256, 256, 0, stream>>>(n3_f, mlp_out, fn_g, fn_b, out);
}